// Round 1
// baseline (4362.614 us; speedup 1.0000x reference)
//
#include <hip/hip_runtime.h>
#include <math.h>

// ---------------------------------------------------------------------------
// AnticipatoryRestaurantGNN: 4x TransformerConv(HID=256, heads=4, C=64,
// edge_dim=16, beta=True) + BatchNorm + LeakyReLU(0.1), then mean/sum pool
// over 64 graphs + linear head.  Round 1: correctness-first fp32.
// ---------------------------------------------------------------------------

#define HID 256
#define CPH 64      // channels per head
#define NHEAD 4
#define EPS 1e-5f

// ---------------- CSR build (by dst; dst reused across all 4 layers) -------
__global__ void k_count(const int* __restrict__ dst, int* __restrict__ deg, int n) {
  int i = blockIdx.x * 256 + threadIdx.x;
  if (i < n) atomicAdd(&deg[dst[i]], 1);
}

__global__ void k_scan(const int* __restrict__ deg, int* __restrict__ row_ptr, int n) {
  __shared__ int sd[1024];
  __shared__ int carry;
  int t = threadIdx.x;
  if (t == 0) { carry = 0; row_ptr[0] = 0; }
  __syncthreads();
  for (int base = 0; base < n; base += 1024) {
    int v = (base + t < n) ? deg[base + t] : 0;
    sd[t] = v;
    __syncthreads();
    for (int off = 1; off < 1024; off <<= 1) {
      int xv = (t >= off) ? sd[t - off] : 0;
      __syncthreads();
      sd[t] += xv;
      __syncthreads();
    }
    int incl = sd[t] + carry;
    if (base + t < n) row_ptr[base + t + 1] = incl;
    __syncthreads();
    if (t == 1023) carry = incl;
    __syncthreads();
  }
}

__global__ void k_scatter(const int* __restrict__ dst, const int* __restrict__ row_ptr,
                          int* __restrict__ fill, int* __restrict__ csr, int n) {
  int i = blockIdx.x * 256 + threadIdx.x;
  if (i < n) {
    int d = dst[i];
    int pos = atomicAdd(&fill[d], 1);
    csr[row_ptr[d] + pos] = i;
  }
}

// ---------------- fp32 tiled GEMM: C[M,Nd] = A[M,Kd] @ B[Kd,Nd] + bias -----
#define BM 128
#define BN 64
#define BK 16
__global__ __launch_bounds__(256) void k_gemm(
    const float* __restrict__ A, const float* __restrict__ B,
    const float* __restrict__ bias, float* __restrict__ C,
    int M, int Kd, int Nd) {
  __shared__ float As[BK][BM + 4];
  __shared__ float Bs[BK][BN + 4];
  int t = threadIdx.x;
  int tx = t & 15, ty = t >> 4;
  int row0 = blockIdx.y * BM, col0 = blockIdx.x * BN;
  float acc[8][4] = {};
  for (int k0 = 0; k0 < Kd; k0 += BK) {
#pragma unroll
    for (int i = 0; i < 2; ++i) {
      int idx = t + i * 256;           // 512 float4 loads cover 128x16
      int r = idx >> 2, kk = (idx & 3) * 4;
      float4 a = make_float4(0.f, 0.f, 0.f, 0.f);
      if (row0 + r < M) a = *(const float4*)(A + (size_t)(row0 + r) * Kd + k0 + kk);
      As[kk + 0][r] = a.x; As[kk + 1][r] = a.y; As[kk + 2][r] = a.z; As[kk + 3][r] = a.w;
    }
    {
      int kk = t >> 4, cc = (t & 15) * 4;  // 256 float4 loads cover 16x64
      float4 b = *(const float4*)(B + (size_t)(k0 + kk) * Nd + col0 + cc);
      Bs[kk][cc] = b.x; Bs[kk][cc + 1] = b.y; Bs[kk][cc + 2] = b.z; Bs[kk][cc + 3] = b.w;
    }
    __syncthreads();
#pragma unroll
    for (int kk = 0; kk < BK; ++kk) {
      float ar[8], br[4];
#pragma unroll
      for (int i = 0; i < 8; ++i) ar[i] = As[kk][ty * 8 + i];
#pragma unroll
      for (int j = 0; j < 4; ++j) br[j] = Bs[kk][tx * 4 + j];
#pragma unroll
      for (int i = 0; i < 8; ++i)
#pragma unroll
        for (int j = 0; j < 4; ++j) acc[i][j] += ar[i] * br[j];
    }
    __syncthreads();
  }
#pragma unroll
  for (int i = 0; i < 8; ++i) {
    int r = row0 + ty * 8 + i;
    if (r < M) {
      int c = col0 + tx * 4;
      float4 o;
      o.x = acc[i][0] + bias[c + 0];
      o.y = acc[i][1] + bias[c + 1];
      o.z = acc[i][2] + bias[c + 2];
      o.w = acc[i][3] + bias[c + 3];
      *(float4*)(C + (size_t)r * Nd + c) = o;
    }
  }
}

// ---------------- attention: one wave per dst node -------------------------
// lane l handles channels 4l..4l+3  (head = l/16).  We (16x256) cached in
// registers: wreg[t] = We[t][4l..4l+3].  Two passes over incident edges:
// pass1 -> per-head max of alpha, pass2 -> denom and weighted V accumulation
// (softmax normalization applied at the end).  out may alias Q (each wave
// reads only its own Q row before writing its own out row).
__global__ __launch_bounds__(256) void k_attn(
    const float* Q, const float* __restrict__ Km, const float* __restrict__ Vm,
    const float* __restrict__ ea_g, const int* __restrict__ srcA,
    const float* __restrict__ We_l, const float* __restrict__ be_l,
    const int* __restrict__ row_ptr, const int* __restrict__ csr,
    float* outp, int nNodes) {
  int t = threadIdx.x;
  int lane = t & 63;
  int n = blockIdx.x * 4 + (t >> 6);
  if (n >= nNodes) return;
  float4 wreg[16];
#pragma unroll
  for (int tt = 0; tt < 16; ++tt) wreg[tt] = *(const float4*)(We_l + tt * 256 + 4 * lane);
  float4 be4 = *(const float4*)(be_l + 4 * lane);
  float4 q = *(const float4*)(Q + (size_t)n * 256 + 4 * lane);
  int beg = row_ptr[n], end = row_ptr[n + 1];

  float m = -INFINITY;
  for (int i = beg; i < end; ++i) {
    int e = csr[i];
    int s = srcA[e];
    float4 k4 = *(const float4*)(Km + (size_t)s * 256 + 4 * lane);
    const float4* eap = (const float4*)(ea_g + (size_t)e * 16);
    float4 ev = be4;
#pragma unroll
    for (int c4 = 0; c4 < 4; ++c4) {
      float4 ea = eap[c4];
      float av[4] = {ea.x, ea.y, ea.z, ea.w};
#pragma unroll
      for (int j = 0; j < 4; ++j) {
        float a = av[j];
        float4 w = wreg[c4 * 4 + j];
        ev.x += a * w.x; ev.y += a * w.y; ev.z += a * w.z; ev.w += a * w.w;
      }
    }
    float p = q.x * (k4.x + ev.x) + q.y * (k4.y + ev.y) +
              q.z * (k4.z + ev.z) + q.w * (k4.w + ev.w);
    p += __shfl_xor(p, 1, 64);
    p += __shfl_xor(p, 2, 64);
    p += __shfl_xor(p, 4, 64);
    p += __shfl_xor(p, 8, 64);
    p *= 0.125f;                 // 1/sqrt(64)
    m = fmaxf(m, p);
  }

  float4 acc = make_float4(0.f, 0.f, 0.f, 0.f);
  float denom = 0.f;
  for (int i = beg; i < end; ++i) {
    int e = csr[i];
    int s = srcA[e];
    float4 k4 = *(const float4*)(Km + (size_t)s * 256 + 4 * lane);
    float4 v4 = *(const float4*)(Vm + (size_t)s * 256 + 4 * lane);
    const float4* eap = (const float4*)(ea_g + (size_t)e * 16);
    float4 ev = be4;
#pragma unroll
    for (int c4 = 0; c4 < 4; ++c4) {
      float4 ea = eap[c4];
      float av[4] = {ea.x, ea.y, ea.z, ea.w};
#pragma unroll
      for (int j = 0; j < 4; ++j) {
        float a = av[j];
        float4 w = wreg[c4 * 4 + j];
        ev.x += a * w.x; ev.y += a * w.y; ev.z += a * w.z; ev.w += a * w.w;
      }
    }
    float p = q.x * (k4.x + ev.x) + q.y * (k4.y + ev.y) +
              q.z * (k4.z + ev.z) + q.w * (k4.w + ev.w);
    p += __shfl_xor(p, 1, 64);
    p += __shfl_xor(p, 2, 64);
    p += __shfl_xor(p, 4, 64);
    p += __shfl_xor(p, 8, 64);
    p *= 0.125f;
    float w = expf(p - m);
    denom += w;
    acc.x += w * (v4.x + ev.x);
    acc.y += w * (v4.y + ev.y);
    acc.z += w * (v4.z + ev.z);
    acc.w += w * (v4.w + ev.w);
  }
  float inv = (end > beg) ? 1.0f / denom : 0.0f;
  float4 o = make_float4(acc.x * inv, acc.y * inv, acc.z * inv, acc.w * inv);
  *(float4*)(outp + (size_t)n * 256 + 4 * lane) = o;
}

// ---------------- beta gate + blend: one wave per node ---------------------
__global__ __launch_bounds__(256) void k_blend(
    const float* op, const float* __restrict__ Sp, const float* __restrict__ Wb,
    float* __restrict__ xout, int nNodes) {
  __shared__ float sWb[768];
  int t = threadIdx.x;
  sWb[t] = Wb[t];
  sWb[t + 256] = Wb[t + 256];
  sWb[t + 512] = Wb[t + 512];
  __syncthreads();
  int lane = t & 63;
  int n = blockIdx.x * 4 + (t >> 6);
  if (n >= nNodes) return;
  float4 o = *(const float4*)(op + (size_t)n * 256 + 4 * lane);
  float4 r = *(const float4*)(Sp + (size_t)n * 256 + 4 * lane);
  int c = 4 * lane;
  float z = o.x * sWb[c] + o.y * sWb[c + 1] + o.z * sWb[c + 2] + o.w * sWb[c + 3]
          + r.x * sWb[256 + c] + r.y * sWb[257 + c] + r.z * sWb[258 + c] + r.w * sWb[259 + c]
          + (o.x - r.x) * sWb[512 + c] + (o.y - r.y) * sWb[513 + c]
          + (o.z - r.z) * sWb[514 + c] + (o.w - r.w) * sWb[515 + c];
#pragma unroll
  for (int off = 1; off < 64; off <<= 1) z += __shfl_xor(z, off, 64);
  float beta = 1.0f / (1.0f + expf(-z));
  float4 xn;
  xn.x = beta * r.x + (1.f - beta) * o.x;
  xn.y = beta * r.y + (1.f - beta) * o.y;
  xn.z = beta * r.z + (1.f - beta) * o.z;
  xn.w = beta * r.w + (1.f - beta) * o.w;
  *(float4*)(xout + (size_t)n * 256 + 4 * lane) = xn;
}

// ---------------- batchnorm ------------------------------------------------
__global__ void k_bnstats(const float* __restrict__ x, float* __restrict__ sums,
                          float* __restrict__ sums2, int nRows) {
  int c = threadIdx.x;
  int rpb = (nRows + gridDim.x - 1) / gridDim.x;
  int r0 = blockIdx.x * rpb;
  int r1 = min(nRows, r0 + rpb);
  float s = 0.f, s2 = 0.f;
  for (int r = r0; r < r1; ++r) {
    float v = x[(size_t)r * 256 + c];
    s += v;
    s2 += v * v;
  }
  atomicAdd(&sums[c], s);
  atomicAdd(&sums2[c], s2);
}

__global__ void k_bnapply(float* __restrict__ x, const float* __restrict__ sums,
                          const float* __restrict__ sums2, const float* __restrict__ gamma,
                          const float* __restrict__ betap, int nRows) {
  int idx = blockIdx.x * 256 + threadIdx.x;
  if (idx >= nRows * 256) return;
  int c = idx & 255;
  float invN = 1.0f / (float)nRows;
  float mu = sums[c] * invN;
  float var = sums2[c] * invN - mu * mu;
  float v = (x[idx] - mu) * rsqrtf(var + EPS) * gamma[c] + betap[c];
  x[idx] = v >= 0.f ? v : 0.1f * v;   // LeakyReLU(0.1)
}

// ---------------- pooling + head -------------------------------------------
__global__ void k_pool(const float* __restrict__ x, const int* __restrict__ batch,
                       float* __restrict__ pool, int nRows) {
  int c = threadIdx.x;
  int rpb = (nRows + gridDim.x - 1) / gridDim.x;
  int r0 = blockIdx.x * rpb;
  int r1 = min(nRows, r0 + rpb);
  float acc = 0.f;
  int gc = -1;
  for (int r = r0; r < r1; ++r) {
    int g = batch[r];
    if (g != gc) {
      if (gc >= 0) atomicAdd(&pool[gc * 256 + c], acc);
      acc = 0.f;
      gc = g;
    }
    acc += x[(size_t)r * 256 + c];
  }
  if (gc >= 0) atomicAdd(&pool[gc * 256 + c], acc);
}

__global__ void k_counts(const int* __restrict__ batch, float* __restrict__ counts, int n) {
  int i = blockIdx.x * 256 + threadIdx.x;
  if (i < n) atomicAdd(&counts[batch[i]], 1.0f);
}

__global__ void k_head(const float* __restrict__ pool, const float* __restrict__ counts,
                       const float* __restrict__ hW, const float* __restrict__ hb,
                       float* __restrict__ outp) {
  int g = blockIdx.x, lane = threadIdx.x;
  float cnt = fmaxf(counts[g], 1.0f);
  float z = 0.f;
#pragma unroll
  for (int i = 0; i < 4; ++i) {
    int c = lane + i * 64;
    float s = pool[g * 256 + c];
    z += (s / cnt) * hW[c] + s * hW[256 + c];
  }
#pragma unroll
  for (int off = 1; off < 64; off <<= 1) z += __shfl_xor(z, off, 64);
  if (lane == 0) outp[g] = z + hb[0];
}

// ---------------------------------------------------------------------------
extern "C" void kernel_launch(void* const* d_in, const int* in_sizes, int n_in,
                              void* d_out, int out_size, void* d_ws, size_t ws_size,
                              hipStream_t stream) {
  const float* node_features = (const float*)d_in[0];
  const int*   edge_index    = (const int*)d_in[1];
  const float* edge_attr     = (const float*)d_in[2];
  const int*   batch         = (const int*)d_in[3];
  const float* proj_W  = (const float*)d_in[4];
  const float* proj_b  = (const float*)d_in[5];
  const float* Wq      = (const float*)d_in[6];
  const float* bq      = (const float*)d_in[7];
  const float* Wk      = (const float*)d_in[8];
  const float* bk      = (const float*)d_in[9];
  const float* Wv      = (const float*)d_in[10];
  const float* bv      = (const float*)d_in[11];
  const float* We      = (const float*)d_in[12];
  const float* be      = (const float*)d_in[13];
  const float* Wskip   = (const float*)d_in[14];
  const float* bskip   = (const float*)d_in[15];
  const float* Wbeta   = (const float*)d_in[16];
  const float* bn_gamma= (const float*)d_in[17];
  const float* bn_beta = (const float*)d_in[18];
  const float* head_W  = (const float*)d_in[19];
  const float* head_b  = (const float*)d_in[20];
  float* out_dev = (float*)d_out;

  const int Nn = in_sizes[0] / 64;   // 50000
  const int Ee = in_sizes[1] / 2;    // 500000
  const int Gg = out_size;           // 64

  char* ws = (char*)d_ws;
  size_t off = 0;
  auto alloc = [&](size_t bytes) -> void* {
    void* p = ws + off;
    off += (bytes + 255) & ~(size_t)255;
    return p;
  };
  float* xb = (float*)alloc((size_t)Nn * 256 * 4);
  float* Qb = (float*)alloc((size_t)Nn * 256 * 4);  // also attention output
  float* Kb = (float*)alloc((size_t)Nn * 256 * 4);
  float* Vb = (float*)alloc((size_t)Nn * 256 * 4);
  float* Sb = (float*)alloc((size_t)Nn * 256 * 4);
  float* bnstat = (float*)alloc(512 * 4);
  float* pool   = (float*)alloc((size_t)Gg * 256 * 4);
  float* counts = (float*)alloc((size_t)Gg * 4);
  int* deg     = (int*)alloc((size_t)Nn * 4);
  int* fill    = (int*)alloc((size_t)Nn * 4);
  int* row_ptr = (int*)alloc((size_t)(Nn + 1) * 4);
  int* csr     = (int*)alloc((size_t)Ee * 4);
  (void)ws_size; (void)n_in;

  const int* srcA = edge_index;
  const int* dstA = edge_index + Ee;

  // CSR build by dst
  hipMemsetAsync(deg, 0, (size_t)Nn * 4, stream);
  hipMemsetAsync(fill, 0, (size_t)Nn * 4, stream);
  k_count<<<(Ee + 255) / 256, 256, 0, stream>>>(dstA, deg, Ee);
  k_scan<<<1, 1024, 0, stream>>>(deg, row_ptr, Nn);
  k_scatter<<<(Ee + 255) / 256, 256, 0, stream>>>(dstA, row_ptr, fill, csr, Ee);

  dim3 gemm_grid(256 / BN, (Nn + BM - 1) / BM);
  // input projection
  k_gemm<<<gemm_grid, 256, 0, stream>>>(node_features, proj_W, proj_b, xb, Nn, 64, 256);

  int nodeBlocks = (Nn + 3) / 4;
  for (int l = 0; l < 4; ++l) {
    const float* Wq_l = Wq + (size_t)l * 65536;
    const float* Wk_l = Wk + (size_t)l * 65536;
    const float* Wv_l = Wv + (size_t)l * 65536;
    const float* Ws_l = Wskip + (size_t)l * 65536;
    k_gemm<<<gemm_grid, 256, 0, stream>>>(xb, Wq_l, bq + l * 256, Qb, Nn, 256, 256);
    k_gemm<<<gemm_grid, 256, 0, stream>>>(xb, Wk_l, bk + l * 256, Kb, Nn, 256, 256);
    k_gemm<<<gemm_grid, 256, 0, stream>>>(xb, Wv_l, bv + l * 256, Vb, Nn, 256, 256);
    k_gemm<<<gemm_grid, 256, 0, stream>>>(xb, Ws_l, bskip + l * 256, Sb, Nn, 256, 256);

    k_attn<<<nodeBlocks, 256, 0, stream>>>(Qb, Kb, Vb, edge_attr, srcA,
                                           We + (size_t)l * 4096, be + l * 256,
                                           row_ptr, csr, Qb /*out alias*/, Nn);
    k_blend<<<nodeBlocks, 256, 0, stream>>>(Qb, Sb, Wbeta + (size_t)l * 768, xb, Nn);

    hipMemsetAsync(bnstat, 0, 512 * 4, stream);
    k_bnstats<<<256, 256, 0, stream>>>(xb, bnstat, bnstat + 256, Nn);
    k_bnapply<<<Nn, 256, 0, stream>>>(xb, bnstat, bnstat + 256,
                                      bn_gamma + l * 256, bn_beta + l * 256, Nn);
  }

  hipMemsetAsync(pool, 0, (size_t)Gg * 256 * 4, stream);
  hipMemsetAsync(counts, 0, (size_t)Gg * 4, stream);
  k_pool<<<256, 256, 0, stream>>>(xb, batch, pool, Nn);
  k_counts<<<(Nn + 255) / 256, 256, 0, stream>>>(batch, counts, Nn);
  k_head<<<Gg, 64, 0, stream>>>(pool, counts, head_W, head_b, out_dev);
}

// Round 2
// 2837.464 us; speedup vs baseline: 1.5375x; 1.5375x over previous
//
#include <hip/hip_runtime.h>
#include <math.h>

// ---------------------------------------------------------------------------
// AnticipatoryRestaurantGNN round 2:
//  - fused Q|K|V|S bf16 MFMA GEMM per layer (16x16x32 bf16, XOR-swizzled LDS)
//  - single-pass online-softmax attention with bf16 K/V gathers
// ---------------------------------------------------------------------------

#define EPS 1e-5f
typedef unsigned short ushort_t;
typedef unsigned int uint_t;

using f32x4 = __attribute__((ext_vector_type(4))) float;
using s16x8 = __attribute__((ext_vector_type(8))) short;

__device__ __forceinline__ ushort_t f2bf(float f) {
  union { float f; uint_t u; } v; v.f = f;
  uint_t u = v.u;
  uint_t r = (u + 0x7FFFu + ((u >> 16) & 1u)) >> 16;   // RNE
  return (ushort_t)r;
}
__device__ __forceinline__ float bf2f(ushort_t h) {
  union { uint_t u; float f; } v; v.u = ((uint_t)h) << 16;
  return v.f;
}

// ---------------- CSR build (by dst; dst reused across all 4 layers) -------
__global__ void k_count(const int* __restrict__ dst, int* __restrict__ deg, int n) {
  int i = blockIdx.x * 256 + threadIdx.x;
  if (i < n) atomicAdd(&deg[dst[i]], 1);
}

__global__ void k_scan(const int* __restrict__ deg, int* __restrict__ row_ptr, int n) {
  __shared__ int sd[1024];
  __shared__ int carry;
  int t = threadIdx.x;
  if (t == 0) { carry = 0; row_ptr[0] = 0; }
  __syncthreads();
  for (int base = 0; base < n; base += 1024) {
    int v = (base + t < n) ? deg[base + t] : 0;
    sd[t] = v;
    __syncthreads();
    for (int off = 1; off < 1024; off <<= 1) {
      int xv = (t >= off) ? sd[t - off] : 0;
      __syncthreads();
      sd[t] += xv;
      __syncthreads();
    }
    int incl = sd[t] + carry;
    if (base + t < n) row_ptr[base + t + 1] = incl;
    __syncthreads();
    if (t == 1023) carry = incl;
    __syncthreads();
  }
}

__global__ void k_scatter(const int* __restrict__ dst, const int* __restrict__ row_ptr,
                          int* __restrict__ fill, int* __restrict__ csr, int n) {
  int i = blockIdx.x * 256 + threadIdx.x;
  if (i < n) {
    int d = dst[i];
    int pos = atomicAdd(&fill[d], 1);
    csr[row_ptr[d] + pos] = i;
  }
}

// ---------------- weight convert: Wcat_t[l][n=1024][k=256] bf16 ------------
__global__ void k_wconv(const float* __restrict__ Wq, const float* __restrict__ Wk,
                        const float* __restrict__ Wv, const float* __restrict__ Ws,
                        ushort_t* __restrict__ Wcat_t) {
  __shared__ float tile[32][33];
  int l = blockIdx.z >> 2, sel = blockIdx.z & 3;
  const float* W = (sel == 0) ? Wq : (sel == 1) ? Wk : (sel == 2) ? Wv : Ws;
  W += (size_t)l * 65536;
  int k0 = blockIdx.x * 32, n0 = blockIdx.y * 32;
  int tx = threadIdx.x, ty = threadIdx.y;           // 32 x 8
#pragma unroll
  for (int i = 0; i < 32; i += 8) tile[ty + i][tx] = W[(size_t)(k0 + ty + i) * 256 + n0 + tx];
  __syncthreads();
  ushort_t* dst = Wcat_t + (size_t)l * 262144 + (size_t)(sel * 256 + n0) * 256 + k0;
#pragma unroll
  for (int i = 0; i < 32; i += 8) dst[(size_t)(ty + i) * 256 + tx] = f2bf(tile[tx][ty + i]);
}

__global__ void k_bconv(const float* __restrict__ bq, const float* __restrict__ bk,
                        const float* __restrict__ bv, const float* __restrict__ bs,
                        float* __restrict__ bias_cat) {
  int idx = blockIdx.x * 256 + threadIdx.x;   // 4096 total
  if (idx >= 4096) return;
  int l = idx >> 10, sel = (idx >> 8) & 3, c = idx & 255;
  const float* p = (sel == 0) ? bq : (sel == 1) ? bk : (sel == 2) ? bv : bs;
  bias_cat[idx] = p[l * 256 + c];
}

// ---------------- fp32 tiled GEMM (input projection only) ------------------
#define BM 128
#define BN 64
#define BK 16
__global__ __launch_bounds__(256) void k_gemm(
    const float* __restrict__ A, const float* __restrict__ B,
    const float* __restrict__ bias, float* __restrict__ C,
    ushort_t* __restrict__ C16, int M, int Kd, int Nd) {
  __shared__ float As[BK][BM + 4];
  __shared__ float Bs[BK][BN + 4];
  int t = threadIdx.x;
  int tx = t & 15, ty = t >> 4;
  int row0 = blockIdx.y * BM, col0 = blockIdx.x * BN;
  float acc[8][4] = {};
  for (int k0 = 0; k0 < Kd; k0 += BK) {
#pragma unroll
    for (int i = 0; i < 2; ++i) {
      int idx = t + i * 256;
      int r = idx >> 2, kk = (idx & 3) * 4;
      float4 a = make_float4(0.f, 0.f, 0.f, 0.f);
      if (row0 + r < M) a = *(const float4*)(A + (size_t)(row0 + r) * Kd + k0 + kk);
      As[kk + 0][r] = a.x; As[kk + 1][r] = a.y; As[kk + 2][r] = a.z; As[kk + 3][r] = a.w;
    }
    {
      int kk = t >> 4, cc = (t & 15) * 4;
      float4 b = *(const float4*)(B + (size_t)(k0 + kk) * Nd + col0 + cc);
      Bs[kk][cc] = b.x; Bs[kk][cc + 1] = b.y; Bs[kk][cc + 2] = b.z; Bs[kk][cc + 3] = b.w;
    }
    __syncthreads();
#pragma unroll
    for (int kk = 0; kk < BK; ++kk) {
      float ar[8], br[4];
#pragma unroll
      for (int i = 0; i < 8; ++i) ar[i] = As[kk][ty * 8 + i];
#pragma unroll
      for (int j = 0; j < 4; ++j) br[j] = Bs[kk][tx * 4 + j];
#pragma unroll
      for (int i = 0; i < 8; ++i)
#pragma unroll
        for (int j = 0; j < 4; ++j) acc[i][j] += ar[i] * br[j];
    }
    __syncthreads();
  }
#pragma unroll
  for (int i = 0; i < 8; ++i) {
    int r = row0 + ty * 8 + i;
    if (r < M) {
      int c = col0 + tx * 4;
      float4 o;
      o.x = acc[i][0] + bias[c + 0];
      o.y = acc[i][1] + bias[c + 1];
      o.z = acc[i][2] + bias[c + 2];
      o.w = acc[i][3] + bias[c + 3];
      *(float4*)(C + (size_t)r * Nd + c) = o;
      ushort4 h;
      h.x = f2bf(o.x); h.y = f2bf(o.y); h.z = f2bf(o.z); h.w = f2bf(o.w);
      *(ushort4*)(C16 + (size_t)r * Nd + c) = h;
    }
  }
}

// ---------------- fused QKVS bf16 MFMA GEMM --------------------------------
// C[M x 1024] = A[M x 256] @ Bt^T  (Bt is [1024][256], k-contiguous)
// tile 128x128, BK=64, 4 waves of 2x2 -> each wave 64x64 (4x4 MFMA tiles).
// LDS layout: 16B granules, data (row r, k-chunk c of 8) stored at granule
// r*8 + (c ^ (r&7))  -> ds_read_b128 spread over all bank groups.
__global__ __launch_bounds__(256) void k_qkvs(
    const ushort_t* __restrict__ A, const ushort_t* __restrict__ Bt,
    const float* __restrict__ bias, float* __restrict__ Qb,
    ushort_t* __restrict__ Kb16, ushort_t* __restrict__ Vb16,
    float* __restrict__ Sb, int M) {
  __shared__ short lds_a[8192];   // 128 x 64 bf16 (swizzled granules)
  __shared__ short lds_b[8192];
  int t = threadIdx.x;
  int lane = t & 63, wv = t >> 6;
  int row0 = blockIdx.y * 128, col0 = blockIdx.x * 128;

  int4 areg[4], breg[4];
  // staging coords: granule g = i*256 + t  -> r=g>>3, c'=g&7, c=c'^(r&7)
  int sr[4], sc[4];
#pragma unroll
  for (int i = 0; i < 4; ++i) {
    int g = i * 256 + t;
    sr[i] = g >> 3;
    sc[i] = (g & 7) ^ (sr[i] & 7);
  }
  auto load_stage = [&](int kk) {
    int k0 = kk * 64;
#pragma unroll
    for (int i = 0; i < 4; ++i) {
      int gr = row0 + sr[i]; if (gr > M - 1) gr = M - 1;
      areg[i] = *(const int4*)(A + (size_t)gr * 256 + k0 + sc[i] * 8);
      int br = col0 + sr[i];
      breg[i] = *(const int4*)(Bt + (size_t)br * 256 + k0 + sc[i] * 8);
    }
  };

  f32x4 acc[4][4];
#pragma unroll
  for (int im = 0; im < 4; ++im)
#pragma unroll
    for (int in = 0; in < 4; ++in) acc[im][in] = (f32x4){0.f, 0.f, 0.f, 0.f};

  int ln16 = lane & 15, q = lane >> 4;
  int mbase = (wv >> 1) * 64;
  int nbase = (wv & 1) * 64;

  load_stage(0);
  for (int kk = 0; kk < 4; ++kk) {
    if (kk) __syncthreads();
#pragma unroll
    for (int i = 0; i < 4; ++i) {
      ((int4*)lds_a)[i * 256 + t] = areg[i];
      ((int4*)lds_b)[i * 256 + t] = breg[i];
    }
    __syncthreads();
    if (kk < 3) load_stage(kk + 1);
#pragma unroll
    for (int kc = 0; kc < 2; ++kc) {
      s16x8 af[4], bf[4];
      int cq = kc * 4 + q;
#pragma unroll
      for (int im = 0; im < 4; ++im) {
        int r = mbase + im * 16 + ln16;
        af[im] = ((const s16x8*)lds_a)[r * 8 + (cq ^ (r & 7))];
      }
#pragma unroll
      for (int in = 0; in < 4; ++in) {
        int r = nbase + in * 16 + ln16;
        bf[in] = ((const s16x8*)lds_b)[r * 8 + (cq ^ (r & 7))];
      }
#pragma unroll
      for (int im = 0; im < 4; ++im)
#pragma unroll
        for (int in = 0; in < 4; ++in)
          acc[im][in] = __builtin_amdgcn_mfma_f32_16x16x32_bf16(af[im], bf[in], acc[im][in], 0, 0, 0);
    }
  }

  // epilogue: C[m = q*4+j][n = ln16] per tile
#pragma unroll
  for (int in = 0; in < 4; ++in) {
    int ncol = col0 + nbase + in * 16 + ln16;
    int which = ncol >> 8, lc = ncol & 255;
    float bz = bias[ncol];
#pragma unroll
    for (int im = 0; im < 4; ++im) {
#pragma unroll
      for (int j = 0; j < 4; ++j) {
        int mr = row0 + mbase + im * 16 + q * 4 + j;
        if (mr < M) {
          float v = acc[im][in][j] + bz;
          if (which == 0)      Qb[(size_t)mr * 256 + lc] = v;
          else if (which == 1) Kb16[(size_t)mr * 256 + lc] = f2bf(v);
          else if (which == 2) Vb16[(size_t)mr * 256 + lc] = f2bf(v);
          else                 Sb[(size_t)mr * 256 + lc] = v;
        }
      }
    }
  }
}

// ---------------- attention: one wave per dst node, online softmax ---------
__global__ __launch_bounds__(256) void k_attn(
    const float* Qp, const ushort_t* __restrict__ Km, const ushort_t* __restrict__ Vm,
    const float* __restrict__ ea_g, const int* __restrict__ srcA,
    const float* __restrict__ We_l, const float* __restrict__ be_l,
    const int* __restrict__ row_ptr, const int* __restrict__ csr,
    float* outp, int nNodes) {
  int t = threadIdx.x;
  int lane = t & 63;
  int n = blockIdx.x * 4 + (t >> 6);
  if (n >= nNodes) return;
  float4 wreg[16];
#pragma unroll
  for (int tt = 0; tt < 16; ++tt) wreg[tt] = *(const float4*)(We_l + tt * 256 + 4 * lane);
  float4 be4 = *(const float4*)(be_l + 4 * lane);
  float4 qv = *(const float4*)(Qp + (size_t)n * 256 + 4 * lane);
  int beg = row_ptr[n], end = row_ptr[n + 1];

  float m = -INFINITY, denom = 0.f;
  float4 acc = make_float4(0.f, 0.f, 0.f, 0.f);

  int e_next = 0, s_next = 0;
  if (beg < end) { e_next = csr[beg]; s_next = srcA[e_next]; }
  for (int i = beg; i < end; ++i) {
    int e = e_next, s = s_next;
    if (i + 1 < end) { e_next = csr[i + 1]; s_next = srcA[e_next]; }
    ushort4 kh = *(const ushort4*)(Km + (size_t)s * 256 + 4 * lane);
    ushort4 vh = *(const ushort4*)(Vm + (size_t)s * 256 + 4 * lane);
    const float4* eap = (const float4*)(ea_g + (size_t)e * 16);
    float4 ev = be4;
#pragma unroll
    for (int c4 = 0; c4 < 4; ++c4) {
      float4 ea = eap[c4];
      float av[4] = {ea.x, ea.y, ea.z, ea.w};
#pragma unroll
      for (int j = 0; j < 4; ++j) {
        float a = av[j];
        float4 w = wreg[c4 * 4 + j];
        ev.x += a * w.x; ev.y += a * w.y; ev.z += a * w.z; ev.w += a * w.w;
      }
    }
    float kx = bf2f(kh.x) + ev.x, ky = bf2f(kh.y) + ev.y;
    float kz = bf2f(kh.z) + ev.z, kw = bf2f(kh.w) + ev.w;
    float p = qv.x * kx + qv.y * ky + qv.z * kz + qv.w * kw;
    p += __shfl_xor(p, 1, 64);
    p += __shfl_xor(p, 2, 64);
    p += __shfl_xor(p, 4, 64);
    p += __shfl_xor(p, 8, 64);
    p *= 0.125f;                 // 1/sqrt(64)
    float mn = fmaxf(m, p);
    float sc = __expf(m - mn);   // m=-inf first iter -> 0
    float w = __expf(p - mn);
    m = mn;
    denom = denom * sc + w;
    acc.x = acc.x * sc + w * (bf2f(vh.x) + ev.x);
    acc.y = acc.y * sc + w * (bf2f(vh.y) + ev.y);
    acc.z = acc.z * sc + w * (bf2f(vh.z) + ev.z);
    acc.w = acc.w * sc + w * (bf2f(vh.w) + ev.w);
  }
  float inv = (end > beg) ? 1.0f / denom : 0.0f;
  float4 o = make_float4(acc.x * inv, acc.y * inv, acc.z * inv, acc.w * inv);
  *(float4*)(outp + (size_t)n * 256 + 4 * lane) = o;
}

// ---------------- beta gate + blend: one wave per node ---------------------
__global__ __launch_bounds__(256) void k_blend(
    const float* op, const float* __restrict__ Sp, const float* __restrict__ Wb,
    float* __restrict__ xout, int nNodes) {
  __shared__ float sWb[768];
  int t = threadIdx.x;
  sWb[t] = Wb[t];
  sWb[t + 256] = Wb[t + 256];
  sWb[t + 512] = Wb[t + 512];
  __syncthreads();
  int lane = t & 63;
  int n = blockIdx.x * 4 + (t >> 6);
  if (n >= nNodes) return;
  float4 o = *(const float4*)(op + (size_t)n * 256 + 4 * lane);
  float4 r = *(const float4*)(Sp + (size_t)n * 256 + 4 * lane);
  int c = 4 * lane;
  float z = o.x * sWb[c] + o.y * sWb[c + 1] + o.z * sWb[c + 2] + o.w * sWb[c + 3]
          + r.x * sWb[256 + c] + r.y * sWb[257 + c] + r.z * sWb[258 + c] + r.w * sWb[259 + c]
          + (o.x - r.x) * sWb[512 + c] + (o.y - r.y) * sWb[513 + c]
          + (o.z - r.z) * sWb[514 + c] + (o.w - r.w) * sWb[515 + c];
#pragma unroll
  for (int off = 1; off < 64; off <<= 1) z += __shfl_xor(z, off, 64);
  float beta = 1.0f / (1.0f + __expf(-z));
  float4 xn;
  xn.x = beta * r.x + (1.f - beta) * o.x;
  xn.y = beta * r.y + (1.f - beta) * o.y;
  xn.z = beta * r.z + (1.f - beta) * o.z;
  xn.w = beta * r.w + (1.f - beta) * o.w;
  *(float4*)(xout + (size_t)n * 256 + 4 * lane) = xn;
}

// ---------------- batchnorm ------------------------------------------------
__global__ void k_bnstats(const float* __restrict__ x, float* __restrict__ sums,
                          float* __restrict__ sums2, int nRows) {
  int c = threadIdx.x;
  int rpb = (nRows + gridDim.x - 1) / gridDim.x;
  int r0 = blockIdx.x * rpb;
  int r1 = min(nRows, r0 + rpb);
  float s = 0.f, s2 = 0.f;
  for (int r = r0; r < r1; ++r) {
    float v = x[(size_t)r * 256 + c];
    s += v;
    s2 += v * v;
  }
  atomicAdd(&sums[c], s);
  atomicAdd(&sums2[c], s2);
}

__global__ void k_bnapply(float* __restrict__ x, ushort_t* __restrict__ x16,
                          const float* __restrict__ sums, const float* __restrict__ sums2,
                          const float* __restrict__ gamma, const float* __restrict__ betap,
                          int nRows) {
  int idx = blockIdx.x * 256 + threadIdx.x;
  if (idx >= nRows * 256) return;
  int c = idx & 255;
  float invN = 1.0f / (float)nRows;
  float mu = sums[c] * invN;
  float var = sums2[c] * invN - mu * mu;
  float v = (x[idx] - mu) * rsqrtf(var + EPS) * gamma[c] + betap[c];
  v = v >= 0.f ? v : 0.1f * v;   // LeakyReLU(0.1)
  x[idx] = v;
  x16[idx] = f2bf(v);
}

// ---------------- pooling + head -------------------------------------------
__global__ void k_pool(const float* __restrict__ x, const int* __restrict__ batch,
                       float* __restrict__ pool, int nRows) {
  int c = threadIdx.x;
  int rpb = (nRows + gridDim.x - 1) / gridDim.x;
  int r0 = blockIdx.x * rpb;
  int r1 = min(nRows, r0 + rpb);
  float acc = 0.f;
  int gc = -1;
  for (int r = r0; r < r1; ++r) {
    int g = batch[r];
    if (g != gc) {
      if (gc >= 0) atomicAdd(&pool[gc * 256 + c], acc);
      acc = 0.f;
      gc = g;
    }
    acc += x[(size_t)r * 256 + c];
  }
  if (gc >= 0) atomicAdd(&pool[gc * 256 + c], acc);
}

__global__ void k_counts(const int* __restrict__ batch, float* __restrict__ counts, int n) {
  int i = blockIdx.x * 256 + threadIdx.x;
  if (i < n) atomicAdd(&counts[batch[i]], 1.0f);
}

__global__ void k_head(const float* __restrict__ pool, const float* __restrict__ counts,
                       const float* __restrict__ hW, const float* __restrict__ hb,
                       float* __restrict__ outp) {
  int g = blockIdx.x, lane = threadIdx.x;
  float cnt = fmaxf(counts[g], 1.0f);
  float z = 0.f;
#pragma unroll
  for (int i = 0; i < 4; ++i) {
    int c = lane + i * 64;
    float s = pool[g * 256 + c];
    z += (s / cnt) * hW[c] + s * hW[256 + c];
  }
#pragma unroll
  for (int off = 1; off < 64; off <<= 1) z += __shfl_xor(z, off, 64);
  if (lane == 0) outp[g] = z + hb[0];
}

// ---------------------------------------------------------------------------
extern "C" void kernel_launch(void* const* d_in, const int* in_sizes, int n_in,
                              void* d_out, int out_size, void* d_ws, size_t ws_size,
                              hipStream_t stream) {
  const float* node_features = (const float*)d_in[0];
  const int*   edge_index    = (const int*)d_in[1];
  const float* edge_attr     = (const float*)d_in[2];
  const int*   batch         = (const int*)d_in[3];
  const float* proj_W  = (const float*)d_in[4];
  const float* proj_b  = (const float*)d_in[5];
  const float* Wq      = (const float*)d_in[6];
  const float* bq      = (const float*)d_in[7];
  const float* Wk      = (const float*)d_in[8];
  const float* bk      = (const float*)d_in[9];
  const float* Wv      = (const float*)d_in[10];
  const float* bv      = (const float*)d_in[11];
  const float* We      = (const float*)d_in[12];
  const float* be      = (const float*)d_in[13];
  const float* Wskip   = (const float*)d_in[14];
  const float* bskip   = (const float*)d_in[15];
  const float* Wbeta   = (const float*)d_in[16];
  const float* bn_gamma= (const float*)d_in[17];
  const float* bn_beta = (const float*)d_in[18];
  const float* head_W  = (const float*)d_in[19];
  const float* head_b  = (const float*)d_in[20];
  float* out_dev = (float*)d_out;

  const int Nn = in_sizes[0] / 64;   // 50000
  const int Ee = in_sizes[1] / 2;    // 500000
  const int Gg = out_size;           // 64

  char* ws = (char*)d_ws;
  size_t off = 0;
  auto alloc = [&](size_t bytes) -> void* {
    void* p = ws + off;
    off += (bytes + 255) & ~(size_t)255;
    return p;
  };
  float*    xb     = (float*)alloc((size_t)Nn * 256 * 4);
  float*    Qb     = (float*)alloc((size_t)Nn * 256 * 4);  // also attention output
  float*    Sb     = (float*)alloc((size_t)Nn * 256 * 4);
  ushort_t* Kb16   = (ushort_t*)alloc((size_t)Nn * 256 * 2);
  ushort_t* Vb16   = (ushort_t*)alloc((size_t)Nn * 256 * 2);
  ushort_t* xb16   = (ushort_t*)alloc((size_t)Nn * 256 * 2);
  ushort_t* Wcat_t = (ushort_t*)alloc((size_t)4 * 1024 * 256 * 2);
  float*    bias_cat = (float*)alloc((size_t)4 * 1024 * 4);
  float*    bnstat = (float*)alloc(512 * 4);
  float*    pool   = (float*)alloc((size_t)Gg * 256 * 4);
  float*    counts = (float*)alloc((size_t)Gg * 4);
  int* deg     = (int*)alloc((size_t)Nn * 4);
  int* fill    = (int*)alloc((size_t)Nn * 4);
  int* row_ptr = (int*)alloc((size_t)(Nn + 1) * 4);
  int* csr     = (int*)alloc((size_t)Ee * 4);
  (void)ws_size; (void)n_in;

  const int* srcA = edge_index;
  const int* dstA = edge_index + Ee;

  // CSR build by dst
  hipMemsetAsync(deg, 0, (size_t)Nn * 4, stream);
  hipMemsetAsync(fill, 0, (size_t)Nn * 4, stream);
  k_count<<<(Ee + 255) / 256, 256, 0, stream>>>(dstA, deg, Ee);
  k_scan<<<1, 1024, 0, stream>>>(deg, row_ptr, Nn);
  k_scatter<<<(Ee + 255) / 256, 256, 0, stream>>>(dstA, row_ptr, fill, csr, Ee);

  // weight/bias conversion (bf16, transposed concat)
  k_wconv<<<dim3(8, 8, 16), dim3(32, 8), 0, stream>>>(Wq, Wk, Wv, Wskip, Wcat_t);
  k_bconv<<<16, 256, 0, stream>>>(bq, bk, bv, bskip, bias_cat);

  // input projection (fp32) + bf16 mirror
  dim3 gemm_grid(256 / BN, (Nn + BM - 1) / BM);
  k_gemm<<<gemm_grid, 256, 0, stream>>>(node_features, proj_W, proj_b, xb, xb16, Nn, 64, 256);

  int nodeBlocks = (Nn + 3) / 4;
  dim3 qkvs_grid(8, (Nn + 127) / 128);
  for (int l = 0; l < 4; ++l) {
    k_qkvs<<<qkvs_grid, 256, 0, stream>>>(xb16, Wcat_t + (size_t)l * 262144,
                                          bias_cat + l * 1024, Qb, Kb16, Vb16, Sb, Nn);

    k_attn<<<nodeBlocks, 256, 0, stream>>>(Qb, Kb16, Vb16, edge_attr, srcA,
                                           We + (size_t)l * 4096, be + l * 256,
                                           row_ptr, csr, Qb /*out alias*/, Nn);
    k_blend<<<nodeBlocks, 256, 0, stream>>>(Qb, Sb, Wbeta + (size_t)l * 768, xb, Nn);

    hipMemsetAsync(bnstat, 0, 512 * 4, stream);
    k_bnstats<<<256, 256, 0, stream>>>(xb, bnstat, bnstat + 256, Nn);
    k_bnapply<<<Nn, 256, 0, stream>>>(xb, xb16, bnstat, bnstat + 256,
                                      bn_gamma + l * 256, bn_beta + l * 256, Nn);
  }

  hipMemsetAsync(pool, 0, (size_t)Gg * 256 * 4, stream);
  hipMemsetAsync(counts, 0, (size_t)Gg * 4, stream);
  k_pool<<<256, 256, 0, stream>>>(xb, batch, pool, Nn);
  k_counts<<<(Nn + 255) / 256, 256, 0, stream>>>(batch, counts, Nn);
  k_head<<<Gg, 64, 0, stream>>>(pool, counts, head_W, head_b, out_dev);
}

// Round 3
// 1947.624 us; speedup vs baseline: 2.2400x; 1.4569x over previous
//
#include <hip/hip_runtime.h>
#include <math.h>

// ---------------------------------------------------------------------------
// AnticipatoryRestaurantGNN round 3:
//  - binary-search graph counts (was: 300us of serialized atomics)
//  - attention: KV-interleaved single 16B gather/lane, chunked edge-id
//    broadcast + depth-2 prefetch, fused beta-gate/blend epilogue
//  - k_qkvs staging via global_load_lds width=16
// ---------------------------------------------------------------------------

#define EPS 1e-5f
typedef unsigned short ushort_t;
typedef unsigned int uint_t;

using f32x4 = __attribute__((ext_vector_type(4))) float;
using s16x8 = __attribute__((ext_vector_type(8))) short;
using u16x8 = __attribute__((ext_vector_type(8))) unsigned short;

__device__ __forceinline__ ushort_t f2bf(float f) {
  union { float f; uint_t u; } v; v.f = f;
  uint_t u = v.u;
  uint_t r = (u + 0x7FFFu + ((u >> 16) & 1u)) >> 16;   // RNE
  return (ushort_t)r;
}
__device__ __forceinline__ float bf2f(ushort_t h) {
  union { uint_t u; float f; } v; v.u = ((uint_t)h) << 16;
  return v.f;
}

__device__ __forceinline__ void gl_lds16(const void* g, void* l) {
  __builtin_amdgcn_global_load_lds(
      (const __attribute__((address_space(1))) void*)g,
      (__attribute__((address_space(3))) void*)l, 16, 0, 0);
}

// ---------------- CSR build (by dst; dst reused across all 4 layers) -------
__global__ void k_count(const int* __restrict__ dst, int* __restrict__ deg, int n) {
  int i = blockIdx.x * 256 + threadIdx.x;
  if (i < n) atomicAdd(&deg[dst[i]], 1);
}

__global__ void k_scan(const int* __restrict__ deg, int* __restrict__ row_ptr, int n) {
  __shared__ int wsum[16];
  __shared__ int carry_s;
  int t = threadIdx.x, lane = t & 63, w = t >> 6;
  if (t == 0) { carry_s = 0; row_ptr[0] = 0; }
  __syncthreads();
  for (int base = 0; base < n; base += 1024) {
    int v = (base + t < n) ? deg[base + t] : 0;
    int x = v;
#pragma unroll
    for (int off = 1; off < 64; off <<= 1) {
      int y = __shfl_up(x, off, 64);
      if (lane >= off) x += y;
    }
    if (lane == 63) wsum[w] = x;
    __syncthreads();
    if (w == 0 && lane < 16) {
      int s = wsum[lane];
#pragma unroll
      for (int off = 1; off < 16; off <<= 1) {
        int y = __shfl_up(s, off, 64);
        if (lane >= off) s += y;
      }
      wsum[lane] = s;
    }
    __syncthreads();
    int add = (w > 0) ? wsum[w - 1] : 0;
    int incl = x + add + carry_s;
    if (base + t < n) row_ptr[base + t + 1] = incl;
    __syncthreads();
    if (t == 1023) carry_s = incl;
    __syncthreads();
  }
}

__global__ void k_scatter(const int* __restrict__ dst, const int* __restrict__ row_ptr,
                          int* __restrict__ fill, int* __restrict__ csr, int n) {
  int i = blockIdx.x * 256 + threadIdx.x;
  if (i < n) {
    int d = dst[i];
    int pos = atomicAdd(&fill[d], 1);
    csr[row_ptr[d] + pos] = i;
  }
}

// ---------------- weight convert: Wcat_t[l][n=1024][k=256] bf16 ------------
__global__ void k_wconv(const float* __restrict__ Wq, const float* __restrict__ Wk,
                        const float* __restrict__ Wv, const float* __restrict__ Ws,
                        ushort_t* __restrict__ Wcat_t) {
  __shared__ float tile[32][33];
  int l = blockIdx.z >> 2, sel = blockIdx.z & 3;
  const float* W = (sel == 0) ? Wq : (sel == 1) ? Wk : (sel == 2) ? Wv : Ws;
  W += (size_t)l * 65536;
  int k0 = blockIdx.x * 32, n0 = blockIdx.y * 32;
  int tx = threadIdx.x, ty = threadIdx.y;           // 32 x 8
#pragma unroll
  for (int i = 0; i < 32; i += 8) tile[ty + i][tx] = W[(size_t)(k0 + ty + i) * 256 + n0 + tx];
  __syncthreads();
  ushort_t* dst = Wcat_t + (size_t)l * 262144 + (size_t)(sel * 256 + n0) * 256 + k0;
#pragma unroll
  for (int i = 0; i < 32; i += 8) dst[(size_t)(ty + i) * 256 + tx] = f2bf(tile[tx][ty + i]);
}

__global__ void k_bconv(const float* __restrict__ bq, const float* __restrict__ bk,
                        const float* __restrict__ bv, const float* __restrict__ bs,
                        float* __restrict__ bias_cat) {
  int idx = blockIdx.x * 256 + threadIdx.x;   // 4096 total
  if (idx >= 4096) return;
  int l = idx >> 10, sel = (idx >> 8) & 3, c = idx & 255;
  const float* p = (sel == 0) ? bq : (sel == 1) ? bk : (sel == 2) ? bv : bs;
  bias_cat[idx] = p[l * 256 + c];
}

// ---------------- fp32 tiled GEMM (input projection only) ------------------
#define BM 128
#define BN 64
#define BK 16
__global__ __launch_bounds__(256) void k_gemm(
    const float* __restrict__ A, const float* __restrict__ B,
    const float* __restrict__ bias, float* __restrict__ C,
    ushort_t* __restrict__ C16, int M, int Kd, int Nd) {
  __shared__ float As[BK][BM + 4];
  __shared__ float Bs[BK][BN + 4];
  int t = threadIdx.x;
  int tx = t & 15, ty = t >> 4;
  int row0 = blockIdx.y * BM, col0 = blockIdx.x * BN;
  float acc[8][4] = {};
  for (int k0 = 0; k0 < Kd; k0 += BK) {
#pragma unroll
    for (int i = 0; i < 2; ++i) {
      int idx = t + i * 256;
      int r = idx >> 2, kk = (idx & 3) * 4;
      float4 a = make_float4(0.f, 0.f, 0.f, 0.f);
      if (row0 + r < M) a = *(const float4*)(A + (size_t)(row0 + r) * Kd + k0 + kk);
      As[kk + 0][r] = a.x; As[kk + 1][r] = a.y; As[kk + 2][r] = a.z; As[kk + 3][r] = a.w;
    }
    {
      int kk = t >> 4, cc = (t & 15) * 4;
      float4 b = *(const float4*)(B + (size_t)(k0 + kk) * Nd + col0 + cc);
      Bs[kk][cc] = b.x; Bs[kk][cc + 1] = b.y; Bs[kk][cc + 2] = b.z; Bs[kk][cc + 3] = b.w;
    }
    __syncthreads();
#pragma unroll
    for (int kk = 0; kk < BK; ++kk) {
      float ar[8], br[4];
#pragma unroll
      for (int i = 0; i < 8; ++i) ar[i] = As[kk][ty * 8 + i];
#pragma unroll
      for (int j = 0; j < 4; ++j) br[j] = Bs[kk][tx * 4 + j];
#pragma unroll
      for (int i = 0; i < 8; ++i)
#pragma unroll
        for (int j = 0; j < 4; ++j) acc[i][j] += ar[i] * br[j];
    }
    __syncthreads();
  }
#pragma unroll
  for (int i = 0; i < 8; ++i) {
    int r = row0 + ty * 8 + i;
    if (r < M) {
      int c = col0 + tx * 4;
      float4 o;
      o.x = acc[i][0] + bias[c + 0];
      o.y = acc[i][1] + bias[c + 1];
      o.z = acc[i][2] + bias[c + 2];
      o.w = acc[i][3] + bias[c + 3];
      *(float4*)(C + (size_t)r * Nd + c) = o;
      ushort4 h;
      h.x = f2bf(o.x); h.y = f2bf(o.y); h.z = f2bf(o.z); h.w = f2bf(o.w);
      *(ushort4*)(C16 + (size_t)r * Nd + c) = h;
    }
  }
}

// ---------------- fused QKVS bf16 MFMA GEMM --------------------------------
// C[M x 1024] = A[M x 256] @ Bt^T  (Bt is [1024][256], k-contiguous)
// tile 128x128, BK=64, 4 waves of 2x2 -> each wave 64x64 (4x4 MFMA tiles).
// Staging via global_load_lds width=16: LDS granule g = i*256+t (linear in t,
// so dest = wave-uniform base + lane*16); the XOR swizzle is applied to the
// GLOBAL source column, so LDS granule r*8+c' holds column c'^(r&7) and the
// MFMA read side uses granule r*8 + (cq ^ (r&7)) as before.
__global__ __launch_bounds__(256) void k_qkvs(
    const ushort_t* __restrict__ A, const ushort_t* __restrict__ Bt,
    const float* __restrict__ bias, float* __restrict__ Qb,
    ushort_t* __restrict__ KVb, float* __restrict__ Sb, int M) {
  __shared__ short lds_a[8192];   // 128 x 64 bf16 (swizzled granules)
  __shared__ short lds_b[8192];
  int t = threadIdx.x;
  int lane = t & 63, wv = t >> 6;
  int row0 = blockIdx.y * 128, col0 = blockIdx.x * 128;

  f32x4 acc[4][4];
#pragma unroll
  for (int im = 0; im < 4; ++im)
#pragma unroll
    for (int in = 0; in < 4; ++in) acc[im][in] = (f32x4){0.f, 0.f, 0.f, 0.f};

  int ln16 = lane & 15, q = lane >> 4;
  int mbase = (wv >> 1) * 64;
  int nbase = (wv & 1) * 64;

  for (int kk = 0; kk < 4; ++kk) {
    int k0 = kk * 64;
    __syncthreads();          // protect previous iteration's LDS reads
#pragma unroll
    for (int i = 0; i < 4; ++i) {
      int gi = i * 256 + t;
      int r = gi >> 3, c = (gi & 7) ^ (r & 7);
      int gr = row0 + r; if (gr > M - 1) gr = M - 1;
      gl_lds16(A + (size_t)gr * 256 + k0 + c * 8, &((int4*)lds_a)[gi]);
      gl_lds16(Bt + (size_t)(col0 + r) * 256 + k0 + c * 8, &((int4*)lds_b)[gi]);
    }
    __syncthreads();          // drains vmcnt(0) then barrier
#pragma unroll
    for (int kc = 0; kc < 2; ++kc) {
      s16x8 af[4], bf[4];
      int cq = kc * 4 + q;
#pragma unroll
      for (int im = 0; im < 4; ++im) {
        int r = mbase + im * 16 + ln16;
        af[im] = ((const s16x8*)lds_a)[r * 8 + (cq ^ (r & 7))];
      }
#pragma unroll
      for (int in = 0; in < 4; ++in) {
        int r = nbase + in * 16 + ln16;
        bf[in] = ((const s16x8*)lds_b)[r * 8 + (cq ^ (r & 7))];
      }
#pragma unroll
      for (int im = 0; im < 4; ++im)
#pragma unroll
        for (int in = 0; in < 4; ++in)
          acc[im][in] = __builtin_amdgcn_mfma_f32_16x16x32_bf16(af[im], bf[in], acc[im][in], 0, 0, 0);
    }
  }

  // epilogue: C[m = q*4+j][n = ln16] per tile.  K/V interleaved:
  // KVb[node][group g][0..3]=K[4g..4g+3], [4..7]=V[4g..4g+3]  (16B granule)
#pragma unroll
  for (int in = 0; in < 4; ++in) {
    int ncol = col0 + nbase + in * 16 + ln16;
    int which = ncol >> 8, lc = ncol & 255;
    float bz = bias[ncol];
#pragma unroll
    for (int im = 0; im < 4; ++im) {
#pragma unroll
      for (int j = 0; j < 4; ++j) {
        int mr = row0 + mbase + im * 16 + q * 4 + j;
        if (mr < M) {
          float v = acc[im][in][j] + bz;
          if (which == 0)      Qb[(size_t)mr * 256 + lc] = v;
          else if (which == 1) KVb[(size_t)mr * 512 + (lc >> 2) * 8 + (lc & 3)] = f2bf(v);
          else if (which == 2) KVb[(size_t)mr * 512 + (lc >> 2) * 8 + (lc & 3) + 4] = f2bf(v);
          else                 Sb[(size_t)mr * 256 + lc] = v;
        }
      }
    }
  }
}

// ---------------- attention + beta-gate blend: one wave per dst node -------
// lane l handles channels 4l..4l+3 (head = l/16).  Edge ids/srcs loaded 64 at
// a time (lane j -> edge base+j) and broadcast via shfl; KV gathered as one
// 16B load per lane with depth-2 prefetch.  Online softmax; normalization at
// the end; then the beta-gate blend (sigmoid([o|x_r|o-x_r] @ Wb)) fused in.
__global__ __launch_bounds__(256) void k_attn(
    const float* __restrict__ Qp, const ushort_t* __restrict__ KVm,
    const float* __restrict__ ea_g, const int* __restrict__ srcA,
    const float* __restrict__ We_l, const float* __restrict__ be_l,
    const float* __restrict__ Wb, const int* __restrict__ row_ptr,
    const int* __restrict__ csr, const float* __restrict__ Sp,
    float* __restrict__ xout, int nNodes) {
  __shared__ float sWb[768];
  int t = threadIdx.x;
  sWb[t] = Wb[t];
  sWb[t + 256] = Wb[t + 256];
  sWb[t + 512] = Wb[t + 512];
  __syncthreads();
  int lane = t & 63;
  int n = blockIdx.x * 4 + (t >> 6);
  if (n >= nNodes) return;
  float4 wreg[16];
#pragma unroll
  for (int tt = 0; tt < 16; ++tt) wreg[tt] = *(const float4*)(We_l + tt * 256 + 4 * lane);
  float4 be4 = *(const float4*)(be_l + 4 * lane);
  float4 qv = *(const float4*)(Qp + (size_t)n * 256 + 4 * lane);
  int beg = row_ptr[n], end = row_ptr[n + 1];

  float m = -INFINITY, denom = 0.f;
  float4 acc = make_float4(0.f, 0.f, 0.f, 0.f);

  for (int base = beg; base < end; base += 64) {
    int cnt = min(64, end - base);
    int eL = 0, sL = 0;
    if (lane < cnt) { eL = csr[base + lane]; sL = srcA[eL]; }
    u16x8 kv_a, kv_b;
    {
      int s0 = __shfl(sL, 0, 64);
      kv_a = *(const u16x8*)(KVm + (size_t)s0 * 512 + lane * 8);
    }
    if (cnt > 1) {
      int s1 = __shfl(sL, 1, 64);
      kv_b = *(const u16x8*)(KVm + (size_t)s1 * 512 + lane * 8);
    }
    for (int j = 0; j < cnt; ++j) {
      u16x8 kv = kv_a;
      kv_a = kv_b;
      if (j + 2 < cnt) {
        int s2 = __shfl(sL, j + 2, 64);
        kv_b = *(const u16x8*)(KVm + (size_t)s2 * 512 + lane * 8);
      }
      int e = __shfl(eL, j, 64);
      const float4* eap = (const float4*)(ea_g + (size_t)e * 16);
      float4 ev = be4;
#pragma unroll
      for (int c4 = 0; c4 < 4; ++c4) {
        float4 ea = eap[c4];
        float av[4] = {ea.x, ea.y, ea.z, ea.w};
#pragma unroll
        for (int jj = 0; jj < 4; ++jj) {
          float a = av[jj];
          float4 w = wreg[c4 * 4 + jj];
          ev.x += a * w.x; ev.y += a * w.y; ev.z += a * w.z; ev.w += a * w.w;
        }
      }
      float kx = bf2f(kv[0]) + ev.x, ky = bf2f(kv[1]) + ev.y;
      float kz = bf2f(kv[2]) + ev.z, kw = bf2f(kv[3]) + ev.w;
      float p = qv.x * kx + qv.y * ky + qv.z * kz + qv.w * kw;
      p += __shfl_xor(p, 1, 64);
      p += __shfl_xor(p, 2, 64);
      p += __shfl_xor(p, 4, 64);
      p += __shfl_xor(p, 8, 64);
      p *= 0.125f;                 // 1/sqrt(64)
      float mn = fmaxf(m, p);
      float scl = __expf(m - mn);  // m=-inf first iter -> 0
      float w = __expf(p - mn);
      m = mn;
      denom = denom * scl + w;
      acc.x = acc.x * scl + w * (bf2f(kv[4]) + ev.x);
      acc.y = acc.y * scl + w * (bf2f(kv[5]) + ev.y);
      acc.z = acc.z * scl + w * (bf2f(kv[6]) + ev.z);
      acc.w = acc.w * scl + w * (bf2f(kv[7]) + ev.w);
    }
  }
  float inv = (end > beg) ? 1.0f / denom : 0.0f;
  float4 o = make_float4(acc.x * inv, acc.y * inv, acc.z * inv, acc.w * inv);

  // fused beta-gate blend
  float4 r = *(const float4*)(Sp + (size_t)n * 256 + 4 * lane);
  int c = 4 * lane;
  float z = o.x * sWb[c] + o.y * sWb[c + 1] + o.z * sWb[c + 2] + o.w * sWb[c + 3]
          + r.x * sWb[256 + c] + r.y * sWb[257 + c] + r.z * sWb[258 + c] + r.w * sWb[259 + c]
          + (o.x - r.x) * sWb[512 + c] + (o.y - r.y) * sWb[513 + c]
          + (o.z - r.z) * sWb[514 + c] + (o.w - r.w) * sWb[515 + c];
#pragma unroll
  for (int off = 1; off < 64; off <<= 1) z += __shfl_xor(z, off, 64);
  float beta = 1.0f / (1.0f + __expf(-z));
  float4 xn;
  xn.x = beta * r.x + (1.f - beta) * o.x;
  xn.y = beta * r.y + (1.f - beta) * o.y;
  xn.z = beta * r.z + (1.f - beta) * o.z;
  xn.w = beta * r.w + (1.f - beta) * o.w;
  *(float4*)(xout + (size_t)n * 256 + 4 * lane) = xn;
}

// ---------------- batchnorm ------------------------------------------------
__global__ void k_bnstats(const float* __restrict__ x, float* __restrict__ sums,
                          float* __restrict__ sums2, int nRows) {
  int c = threadIdx.x;
  int rpb = (nRows + gridDim.x - 1) / gridDim.x;
  int r0 = blockIdx.x * rpb;
  int r1 = min(nRows, r0 + rpb);
  float s = 0.f, s2 = 0.f;
  for (int r = r0; r < r1; ++r) {
    float v = x[(size_t)r * 256 + c];
    s += v;
    s2 += v * v;
  }
  atomicAdd(&sums[c], s);
  atomicAdd(&sums2[c], s2);
}

__global__ void k_bnapply(float* __restrict__ x, ushort_t* __restrict__ x16,
                          const float* __restrict__ sums, const float* __restrict__ sums2,
                          const float* __restrict__ gamma, const float* __restrict__ betap,
                          int nRows) {
  int idx = blockIdx.x * 256 + threadIdx.x;
  if (idx >= nRows * 256) return;
  int c = idx & 255;
  float invN = 1.0f / (float)nRows;
  float mu = sums[c] * invN;
  float var = sums2[c] * invN - mu * mu;
  float v = (x[idx] - mu) * rsqrtf(var + EPS) * gamma[c] + betap[c];
  v = v >= 0.f ? v : 0.1f * v;   // LeakyReLU(0.1)
  x[idx] = v;
  x16[idx] = f2bf(v);
}

// ---------------- pooling + head -------------------------------------------
__global__ void k_pool(const float* __restrict__ x, const int* __restrict__ batch,
                       float* __restrict__ pool, int nRows) {
  int c = threadIdx.x;
  int rpb = (nRows + gridDim.x - 1) / gridDim.x;
  int r0 = blockIdx.x * rpb;
  int r1 = min(nRows, r0 + rpb);
  float acc = 0.f;
  int gc = -1;
  for (int r = r0; r < r1; ++r) {
    int g = batch[r];
    if (g != gc) {
      if (gc >= 0) atomicAdd(&pool[gc * 256 + c], acc);
      acc = 0.f;
      gc = g;
    }
    acc += x[(size_t)r * 256 + c];
  }
  if (gc >= 0) atomicAdd(&pool[gc * 256 + c], acc);
}

// batch is sorted -> per-graph counts via binary search (no atomics)
__global__ void k_counts_bs(const int* __restrict__ batch, float* __restrict__ counts,
                            int n, int G) {
  int g = threadIdx.x;
  if (g >= G) return;
  int lo = 0, hi = n;
  while (lo < hi) { int mid = (lo + hi) >> 1; if (batch[mid] < g) lo = mid + 1; else hi = mid; }
  int lb = lo;
  lo = 0; hi = n;
  while (lo < hi) { int mid = (lo + hi) >> 1; if (batch[mid] < g + 1) lo = mid + 1; else hi = mid; }
  counts[g] = (float)(lo - lb);
}

__global__ void k_head(const float* __restrict__ pool, const float* __restrict__ counts,
                       const float* __restrict__ hW, const float* __restrict__ hb,
                       float* __restrict__ outp) {
  int g = blockIdx.x, lane = threadIdx.x;
  float cnt = fmaxf(counts[g], 1.0f);
  float z = 0.f;
#pragma unroll
  for (int i = 0; i < 4; ++i) {
    int c = lane + i * 64;
    float s = pool[g * 256 + c];
    z += (s / cnt) * hW[c] + s * hW[256 + c];
  }
#pragma unroll
  for (int off = 1; off < 64; off <<= 1) z += __shfl_xor(z, off, 64);
  if (lane == 0) outp[g] = z + hb[0];
}

// ---------------------------------------------------------------------------
extern "C" void kernel_launch(void* const* d_in, const int* in_sizes, int n_in,
                              void* d_out, int out_size, void* d_ws, size_t ws_size,
                              hipStream_t stream) {
  const float* node_features = (const float*)d_in[0];
  const int*   edge_index    = (const int*)d_in[1];
  const float* edge_attr     = (const float*)d_in[2];
  const int*   batch         = (const int*)d_in[3];
  const float* proj_W  = (const float*)d_in[4];
  const float* proj_b  = (const float*)d_in[5];
  const float* Wq      = (const float*)d_in[6];
  const float* bq      = (const float*)d_in[7];
  const float* Wk      = (const float*)d_in[8];
  const float* bk      = (const float*)d_in[9];
  const float* Wv      = (const float*)d_in[10];
  const float* bv      = (const float*)d_in[11];
  const float* We      = (const float*)d_in[12];
  const float* be      = (const float*)d_in[13];
  const float* Wskip   = (const float*)d_in[14];
  const float* bskip   = (const float*)d_in[15];
  const float* Wbeta   = (const float*)d_in[16];
  const float* bn_gamma= (const float*)d_in[17];
  const float* bn_beta = (const float*)d_in[18];
  const float* head_W  = (const float*)d_in[19];
  const float* head_b  = (const float*)d_in[20];
  float* out_dev = (float*)d_out;

  const int Nn = in_sizes[0] / 64;   // 50000
  const int Ee = in_sizes[1] / 2;    // 500000
  const int Gg = out_size;           // 64

  char* ws = (char*)d_ws;
  size_t off = 0;
  auto alloc = [&](size_t bytes) -> void* {
    void* p = ws + off;
    off += (bytes + 255) & ~(size_t)255;
    return p;
  };
  float*    xb     = (float*)alloc((size_t)Nn * 256 * 4);
  float*    Qb     = (float*)alloc((size_t)Nn * 256 * 4);
  float*    Sb     = (float*)alloc((size_t)Nn * 256 * 4);
  ushort_t* KVb    = (ushort_t*)alloc((size_t)Nn * 512 * 2);   // interleaved K|V
  ushort_t* xb16   = (ushort_t*)alloc((size_t)Nn * 256 * 2);
  ushort_t* Wcat_t = (ushort_t*)alloc((size_t)4 * 1024 * 256 * 2);
  float*    bias_cat = (float*)alloc((size_t)4 * 1024 * 4);
  float*    bnstat = (float*)alloc(512 * 4);
  float*    pool   = (float*)alloc((size_t)Gg * 256 * 4);
  float*    counts = (float*)alloc((size_t)Gg * 4);
  int* deg     = (int*)alloc((size_t)Nn * 4);
  int* fill    = (int*)alloc((size_t)Nn * 4);
  int* row_ptr = (int*)alloc((size_t)(Nn + 1) * 4);
  int* csr     = (int*)alloc((size_t)Ee * 4);
  (void)ws_size; (void)n_in;

  const int* srcA = edge_index;
  const int* dstA = edge_index + Ee;

  // CSR build by dst
  hipMemsetAsync(deg, 0, (size_t)Nn * 4, stream);
  hipMemsetAsync(fill, 0, (size_t)Nn * 4, stream);
  k_count<<<(Ee + 255) / 256, 256, 0, stream>>>(dstA, deg, Ee);
  k_scan<<<1, 1024, 0, stream>>>(deg, row_ptr, Nn);
  k_scatter<<<(Ee + 255) / 256, 256, 0, stream>>>(dstA, row_ptr, fill, csr, Ee);

  // weight/bias conversion (bf16, transposed concat)
  k_wconv<<<dim3(8, 8, 16), dim3(32, 8), 0, stream>>>(Wq, Wk, Wv, Wskip, Wcat_t);
  k_bconv<<<16, 256, 0, stream>>>(bq, bk, bv, bskip, bias_cat);

  // input projection (fp32) + bf16 mirror
  dim3 gemm_grid(256 / BN, (Nn + BM - 1) / BM);
  k_gemm<<<gemm_grid, 256, 0, stream>>>(node_features, proj_W, proj_b, xb, xb16, Nn, 64, 256);

  int nodeBlocks = (Nn + 3) / 4;
  dim3 qkvs_grid(8, (Nn + 127) / 128);
  for (int l = 0; l < 4; ++l) {
    k_qkvs<<<qkvs_grid, 256, 0, stream>>>(xb16, Wcat_t + (size_t)l * 262144,
                                          bias_cat + l * 1024, Qb, KVb, Sb, Nn);

    k_attn<<<nodeBlocks, 256, 0, stream>>>(Qb, KVb, edge_attr, srcA,
                                           We + (size_t)l * 4096, be + l * 256,
                                           Wbeta + (size_t)l * 768,
                                           row_ptr, csr, Sb, xb, Nn);

    hipMemsetAsync(bnstat, 0, 512 * 4, stream);
    k_bnstats<<<256, 256, 0, stream>>>(xb, bnstat, bnstat + 256, Nn);
    k_bnapply<<<Nn, 256, 0, stream>>>(xb, xb16, bnstat, bnstat + 256,
                                      bn_gamma + l * 256, bn_beta + l * 256, Nn);
  }

  hipMemsetAsync(pool, 0, (size_t)Gg * 256 * 4, stream);
  hipMemsetAsync(counts, 0, (size_t)Gg * 4, stream);
  k_pool<<<256, 256, 0, stream>>>(xb, batch, pool, Nn);
  k_counts_bs<<<1, 64, 0, stream>>>(batch, counts, Nn, Gg);
  k_head<<<Gg, 64, 0, stream>>>(pool, counts, head_W, head_b, out_dev);
}

// Round 4
// 1697.247 us; speedup vs baseline: 2.5704x; 1.1475x over previous
//
#include <hip/hip_runtime.h>
#include <math.h>

// ---------------------------------------------------------------------------
// AnticipatoryRestaurantGNN round 4:
//  - k_attn restructured: edge-feature projection moved OUT of the per-edge
//    loop via algebraic decomposition (score: q.e = ea.dq; output: We^T wacc),
//    edge attrs staged to LDS once per chunk, KV gathered with ping-pong
//    register prefetch (groups of 4).  Per-edge VALU ~3x lower, no dependent
//    global loads in the loop.
// ---------------------------------------------------------------------------

#define EPS 1e-5f
typedef unsigned short ushort_t;
typedef unsigned int uint_t;

using f32x4 = __attribute__((ext_vector_type(4))) float;
using s16x8 = __attribute__((ext_vector_type(8))) short;
using u16x8 = __attribute__((ext_vector_type(8))) unsigned short;

__device__ __forceinline__ ushort_t f2bf(float f) {
  union { float f; uint_t u; } v; v.f = f;
  uint_t u = v.u;
  uint_t r = (u + 0x7FFFu + ((u >> 16) & 1u)) >> 16;   // RNE
  return (ushort_t)r;
}
__device__ __forceinline__ float bf2f(ushort_t h) {
  union { uint_t u; float f; } v; v.u = ((uint_t)h) << 16;
  return v.f;
}

__device__ __forceinline__ void gl_lds16(const void* g, void* l) {
  __builtin_amdgcn_global_load_lds(
      (const __attribute__((address_space(1))) void*)g,
      (__attribute__((address_space(3))) void*)l, 16, 0, 0);
}

__device__ __forceinline__ float red16(float x) {
  x += __shfl_xor(x, 1, 64);
  x += __shfl_xor(x, 2, 64);
  x += __shfl_xor(x, 4, 64);
  x += __shfl_xor(x, 8, 64);
  return x;
}

// ---------------- CSR build (by dst; dst reused across all 4 layers) -------
__global__ void k_count(const int* __restrict__ dst, int* __restrict__ deg, int n) {
  int i = blockIdx.x * 256 + threadIdx.x;
  if (i < n) atomicAdd(&deg[dst[i]], 1);
}

__global__ void k_scan(const int* __restrict__ deg, int* __restrict__ row_ptr, int n) {
  __shared__ int wsum[16];
  __shared__ int carry_s;
  int t = threadIdx.x, lane = t & 63, w = t >> 6;
  if (t == 0) { carry_s = 0; row_ptr[0] = 0; }
  __syncthreads();
  for (int base = 0; base < n; base += 1024) {
    int v = (base + t < n) ? deg[base + t] : 0;
    int x = v;
#pragma unroll
    for (int off = 1; off < 64; off <<= 1) {
      int y = __shfl_up(x, off, 64);
      if (lane >= off) x += y;
    }
    if (lane == 63) wsum[w] = x;
    __syncthreads();
    if (w == 0 && lane < 16) {
      int s = wsum[lane];
#pragma unroll
      for (int off = 1; off < 16; off <<= 1) {
        int y = __shfl_up(s, off, 64);
        if (lane >= off) s += y;
      }
      wsum[lane] = s;
    }
    __syncthreads();
    int add = (w > 0) ? wsum[w - 1] : 0;
    int incl = x + add + carry_s;
    if (base + t < n) row_ptr[base + t + 1] = incl;
    __syncthreads();
    if (t == 1023) carry_s = incl;
    __syncthreads();
  }
}

__global__ void k_scatter(const int* __restrict__ dst, const int* __restrict__ row_ptr,
                          int* __restrict__ fill, int* __restrict__ csr, int n) {
  int i = blockIdx.x * 256 + threadIdx.x;
  if (i < n) {
    int d = dst[i];
    int pos = atomicAdd(&fill[d], 1);
    csr[row_ptr[d] + pos] = i;
  }
}

// ---------------- weight convert: Wcat_t[l][n=1024][k=256] bf16 ------------
__global__ void k_wconv(const float* __restrict__ Wq, const float* __restrict__ Wk,
                        const float* __restrict__ Wv, const float* __restrict__ Ws,
                        ushort_t* __restrict__ Wcat_t) {
  __shared__ float tile[32][33];
  int l = blockIdx.z >> 2, sel = blockIdx.z & 3;
  const float* W = (sel == 0) ? Wq : (sel == 1) ? Wk : (sel == 2) ? Wv : Ws;
  W += (size_t)l * 65536;
  int k0 = blockIdx.x * 32, n0 = blockIdx.y * 32;
  int tx = threadIdx.x, ty = threadIdx.y;           // 32 x 8
#pragma unroll
  for (int i = 0; i < 32; i += 8) tile[ty + i][tx] = W[(size_t)(k0 + ty + i) * 256 + n0 + tx];
  __syncthreads();
  ushort_t* dst = Wcat_t + (size_t)l * 262144 + (size_t)(sel * 256 + n0) * 256 + k0;
#pragma unroll
  for (int i = 0; i < 32; i += 8) dst[(size_t)(ty + i) * 256 + tx] = f2bf(tile[tx][ty + i]);
}

__global__ void k_bconv(const float* __restrict__ bq, const float* __restrict__ bk,
                        const float* __restrict__ bv, const float* __restrict__ bs,
                        float* __restrict__ bias_cat) {
  int idx = blockIdx.x * 256 + threadIdx.x;   // 4096 total
  if (idx >= 4096) return;
  int l = idx >> 10, sel = (idx >> 8) & 3, c = idx & 255;
  const float* p = (sel == 0) ? bq : (sel == 1) ? bk : (sel == 2) ? bv : bs;
  bias_cat[idx] = p[l * 256 + c];
}

// ---------------- fp32 tiled GEMM (input projection only) ------------------
#define BM 128
#define BN 64
#define BK 16
__global__ __launch_bounds__(256) void k_gemm(
    const float* __restrict__ A, const float* __restrict__ B,
    const float* __restrict__ bias, float* __restrict__ C,
    ushort_t* __restrict__ C16, int M, int Kd, int Nd) {
  __shared__ float As[BK][BM + 4];
  __shared__ float Bs[BK][BN + 4];
  int t = threadIdx.x;
  int tx = t & 15, ty = t >> 4;
  int row0 = blockIdx.y * BM, col0 = blockIdx.x * BN;
  float acc[8][4] = {};
  for (int k0 = 0; k0 < Kd; k0 += BK) {
#pragma unroll
    for (int i = 0; i < 2; ++i) {
      int idx = t + i * 256;
      int r = idx >> 2, kk = (idx & 3) * 4;
      float4 a = make_float4(0.f, 0.f, 0.f, 0.f);
      if (row0 + r < M) a = *(const float4*)(A + (size_t)(row0 + r) * Kd + k0 + kk);
      As[kk + 0][r] = a.x; As[kk + 1][r] = a.y; As[kk + 2][r] = a.z; As[kk + 3][r] = a.w;
    }
    {
      int kk = t >> 4, cc = (t & 15) * 4;
      float4 b = *(const float4*)(B + (size_t)(k0 + kk) * Nd + col0 + cc);
      Bs[kk][cc] = b.x; Bs[kk][cc + 1] = b.y; Bs[kk][cc + 2] = b.z; Bs[kk][cc + 3] = b.w;
    }
    __syncthreads();
#pragma unroll
    for (int kk = 0; kk < BK; ++kk) {
      float ar[8], br[4];
#pragma unroll
      for (int i = 0; i < 8; ++i) ar[i] = As[kk][ty * 8 + i];
#pragma unroll
      for (int j = 0; j < 4; ++j) br[j] = Bs[kk][tx * 4 + j];
#pragma unroll
      for (int i = 0; i < 8; ++i)
#pragma unroll
        for (int j = 0; j < 4; ++j) acc[i][j] += ar[i] * br[j];
    }
    __syncthreads();
  }
#pragma unroll
  for (int i = 0; i < 8; ++i) {
    int r = row0 + ty * 8 + i;
    if (r < M) {
      int c = col0 + tx * 4;
      float4 o;
      o.x = acc[i][0] + bias[c + 0];
      o.y = acc[i][1] + bias[c + 1];
      o.z = acc[i][2] + bias[c + 2];
      o.w = acc[i][3] + bias[c + 3];
      *(float4*)(C + (size_t)r * Nd + c) = o;
      ushort4 h;
      h.x = f2bf(o.x); h.y = f2bf(o.y); h.z = f2bf(o.z); h.w = f2bf(o.w);
      *(ushort4*)(C16 + (size_t)r * Nd + c) = h;
    }
  }
}

// ---------------- fused QKVS bf16 MFMA GEMM --------------------------------
__global__ __launch_bounds__(256) void k_qkvs(
    const ushort_t* __restrict__ A, const ushort_t* __restrict__ Bt,
    const float* __restrict__ bias, float* __restrict__ Qb,
    ushort_t* __restrict__ KVb, float* __restrict__ Sb, int M) {
  __shared__ short lds_a[8192];   // 128 x 64 bf16 (swizzled granules)
  __shared__ short lds_b[8192];
  int t = threadIdx.x;
  int lane = t & 63, wv = t >> 6;
  int row0 = blockIdx.y * 128, col0 = blockIdx.x * 128;

  f32x4 acc[4][4];
#pragma unroll
  for (int im = 0; im < 4; ++im)
#pragma unroll
    for (int in = 0; in < 4; ++in) acc[im][in] = (f32x4){0.f, 0.f, 0.f, 0.f};

  int ln16 = lane & 15, q = lane >> 4;
  int mbase = (wv >> 1) * 64;
  int nbase = (wv & 1) * 64;

  for (int kk = 0; kk < 4; ++kk) {
    int k0 = kk * 64;
    __syncthreads();          // protect previous iteration's LDS reads
#pragma unroll
    for (int i = 0; i < 4; ++i) {
      int gi = i * 256 + t;
      int r = gi >> 3, c = (gi & 7) ^ (r & 7);
      int gr = row0 + r; if (gr > M - 1) gr = M - 1;
      gl_lds16(A + (size_t)gr * 256 + k0 + c * 8, &((int4*)lds_a)[gi]);
      gl_lds16(Bt + (size_t)(col0 + r) * 256 + k0 + c * 8, &((int4*)lds_b)[gi]);
    }
    __syncthreads();          // drains vmcnt(0) then barrier
#pragma unroll
    for (int kc = 0; kc < 2; ++kc) {
      s16x8 af[4], bf[4];
      int cq = kc * 4 + q;
#pragma unroll
      for (int im = 0; im < 4; ++im) {
        int r = mbase + im * 16 + ln16;
        af[im] = ((const s16x8*)lds_a)[r * 8 + (cq ^ (r & 7))];
      }
#pragma unroll
      for (int in = 0; in < 4; ++in) {
        int r = nbase + in * 16 + ln16;
        bf[in] = ((const s16x8*)lds_b)[r * 8 + (cq ^ (r & 7))];
      }
#pragma unroll
      for (int im = 0; im < 4; ++im)
#pragma unroll
        for (int in = 0; in < 4; ++in)
          acc[im][in] = __builtin_amdgcn_mfma_f32_16x16x32_bf16(af[im], bf[in], acc[im][in], 0, 0, 0);
    }
  }

  // epilogue: C[m = q*4+j][n = ln16] per tile.  K/V interleaved 16B granules.
#pragma unroll
  for (int in = 0; in < 4; ++in) {
    int ncol = col0 + nbase + in * 16 + ln16;
    int which = ncol >> 8, lc = ncol & 255;
    float bz = bias[ncol];
#pragma unroll
    for (int im = 0; im < 4; ++im) {
#pragma unroll
      for (int j = 0; j < 4; ++j) {
        int mr = row0 + mbase + im * 16 + q * 4 + j;
        if (mr < M) {
          float v = acc[im][in][j] + bz;
          if (which == 0)      Qb[(size_t)mr * 256 + lc] = v;
          else if (which == 1) KVb[(size_t)mr * 512 + (lc >> 2) * 8 + (lc & 3)] = f2bf(v);
          else if (which == 2) KVb[(size_t)mr * 512 + (lc >> 2) * 8 + (lc & 3) + 4] = f2bf(v);
          else                 Sb[(size_t)mr * 256 + lc] = v;
        }
      }
    }
  }
}

// ---------------- attention + beta-gate blend: one wave per dst node -------
// Decomposition (exact reassociation):
//   e_j = We^T ea_j + be
//   score_h = qs.K[s] + sum_t ea_j[t]*dq[t,h] + qbe_h        (qs = q/8)
//     dq[t,h] = sum_{c in head h} qs[c] We[t][c]   (lane (h,t) keeps dq)
//   out_c = acc_v[c]/denom + be[c] + (sum_t We[t][c] * wacc[h,t])/denom
//     wacc[h,t] = sum_j w_j * ea_j[t]  (online-rescaled like acc/denom)
// Edge attrs staged to LDS planes (stride 17) once per 64-edge chunk; KV
// gathered via ping-pong register groups of 4 (prefetch next 4 during compute).
__global__ __launch_bounds__(256) void k_attn(
    const float* __restrict__ Qp, const ushort_t* __restrict__ KVm,
    const float* __restrict__ ea_g, const int* __restrict__ srcA,
    const float* __restrict__ We_l, const float* __restrict__ be_l,
    const float* __restrict__ Wb, const int* __restrict__ row_ptr,
    const int* __restrict__ csr, const float* __restrict__ Sp,
    float* __restrict__ xout, int nNodes) {
  __shared__ float sWb[768];
  __shared__ float ea_s[4 * 1088];   // per-wave 64 edges x 17 (padded)
  int t = threadIdx.x;
  sWb[t] = Wb[t];
  sWb[t + 256] = Wb[t + 256];
  sWb[t + 512] = Wb[t + 512];
  // no barrier needed for sWb: each wave writes the full 768 range? No --
  // each thread writes 3 entries; waves cover disjoint quarters.  A block
  // barrier IS needed before use (use is in epilogue; __syncthreads below).
  __syncthreads();
  int lane = t & 63;
  int t16 = lane & 15;
  int n = blockIdx.x * 4 + (t >> 6);
  if (n >= nNodes) return;
  float* eaw = ea_s + (t >> 6) * 1088;

  float4 be4 = *(const float4*)(be_l + 4 * lane);
  float4 qs = *(const float4*)(Qp + (size_t)n * 256 + 4 * lane);
  qs.x *= 0.125f; qs.y *= 0.125f; qs.z *= 0.125f; qs.w *= 0.125f;

  // qbe_h = qs . be (per head)
  float qbe = red16(qs.x * be4.x + qs.y * be4.y + qs.z * be4.z + qs.w * be4.w);

  // dq[t,h]: lane (h,t) keeps its value
  float dqv = 0.f;
#pragma unroll
  for (int tt = 0; tt < 16; ++tt) {
    float4 w4 = *(const float4*)(We_l + tt * 256 + 4 * lane);
    float pt = red16(qs.x * w4.x + qs.y * w4.y + qs.z * w4.z + qs.w * w4.w);
    if (t16 == tt) dqv = pt;
  }

  int beg = row_ptr[n], end = row_ptr[n + 1];
  float m = -INFINITY, denom = 0.f, wacc = 0.f;
  float4 acc = make_float4(0.f, 0.f, 0.f, 0.f);

  for (int base = beg; base < end; base += 64) {
    int cnt = min(64, end - base);
    int eL = 0, sL = 0;
    if (lane < cnt) { eL = csr[base + lane]; sL = srcA[eL]; }
    // stage this chunk's edge attrs into LDS planes
    if (lane < cnt) {
      const float4* eap = (const float4*)(ea_g + (size_t)eL * 16);
      float4 e0 = eap[0], e1 = eap[1], e2 = eap[2], e3 = eap[3];
      float* dst = eaw + lane * 17;
      dst[0] = e0.x; dst[1] = e0.y; dst[2] = e0.z; dst[3] = e0.w;
      dst[4] = e1.x; dst[5] = e1.y; dst[6] = e1.z; dst[7] = e1.w;
      dst[8] = e2.x; dst[9] = e2.y; dst[10] = e2.z; dst[11] = e2.w;
      dst[12] = e3.x; dst[13] = e3.y; dst[14] = e3.z; dst[15] = e3.w;
    }

    u16x8 bufA[4], bufB[4];
    auto ld4 = [&](u16x8* buf, int j0) {
#pragma unroll
      for (int jj = 0; jj < 4; ++jj) {
        int idx = j0 + jj;
        int s = __shfl(sL, idx & 63, 64);
        if (idx < cnt) buf[jj] = *(const u16x8*)(KVm + (size_t)s * 512 + lane * 8);
      }
    };
    auto proc = [&](const u16x8& kv, int idx) {
      float eat = eaw[idx * 17 + t16];
      float part = qs.x * bf2f(kv[0]) + qs.y * bf2f(kv[1]) +
                   qs.z * bf2f(kv[2]) + qs.w * bf2f(kv[3]) + eat * dqv;
      float p = red16(part) + qbe;
      float mn = fmaxf(m, p);
      float scl = __expf(m - mn);   // m=-inf first iter -> 0
      float w = __expf(p - mn);
      m = mn;
      denom = denom * scl + w;
      acc.x = acc.x * scl + w * bf2f(kv[4]);
      acc.y = acc.y * scl + w * bf2f(kv[5]);
      acc.z = acc.z * scl + w * bf2f(kv[6]);
      acc.w = acc.w * scl + w * bf2f(kv[7]);
      wacc = wacc * scl + w * eat;
    };

    ld4(bufA, 0);
    for (int j0 = 0; j0 < cnt; j0 += 8) {
      ld4(bufB, j0 + 4);
#pragma unroll
      for (int jj = 0; jj < 4; ++jj) if (j0 + jj < cnt) proc(bufA[jj], j0 + jj);
      if (j0 + 4 >= cnt) break;
      ld4(bufA, j0 + 8);
#pragma unroll
      for (int jj = 0; jj < 4; ++jj) if (j0 + 4 + jj < cnt) proc(bufB[jj], j0 + 4 + jj);
    }
  }

  float4 o = make_float4(0.f, 0.f, 0.f, 0.f);
  if (end > beg) {
    float inv = 1.0f / denom;
    o.x = acc.x * inv + be4.x;
    o.y = acc.y * inv + be4.y;
    o.z = acc.z * inv + be4.z;
    o.w = acc.w * inv + be4.w;
    int lanebase = lane & 48;
#pragma unroll
    for (int tt = 0; tt < 16; ++tt) {
      float wv = __shfl(wacc, lanebase + tt, 64) * inv;
      float4 w4 = *(const float4*)(We_l + tt * 256 + 4 * lane);
      o.x += wv * w4.x; o.y += wv * w4.y; o.z += wv * w4.z; o.w += wv * w4.w;
    }
  }

  // fused beta-gate blend
  float4 r = *(const float4*)(Sp + (size_t)n * 256 + 4 * lane);
  int c = 4 * lane;
  float z = o.x * sWb[c] + o.y * sWb[c + 1] + o.z * sWb[c + 2] + o.w * sWb[c + 3]
          + r.x * sWb[256 + c] + r.y * sWb[257 + c] + r.z * sWb[258 + c] + r.w * sWb[259 + c]
          + (o.x - r.x) * sWb[512 + c] + (o.y - r.y) * sWb[513 + c]
          + (o.z - r.z) * sWb[514 + c] + (o.w - r.w) * sWb[515 + c];
#pragma unroll
  for (int off = 1; off < 64; off <<= 1) z += __shfl_xor(z, off, 64);
  float beta = 1.0f / (1.0f + __expf(-z));
  float4 xn;
  xn.x = beta * r.x + (1.f - beta) * o.x;
  xn.y = beta * r.y + (1.f - beta) * o.y;
  xn.z = beta * r.z + (1.f - beta) * o.z;
  xn.w = beta * r.w + (1.f - beta) * o.w;
  *(float4*)(xout + (size_t)n * 256 + 4 * lane) = xn;
}

// ---------------- batchnorm ------------------------------------------------
__global__ void k_bnstats(const float* __restrict__ x, float* __restrict__ sums,
                          float* __restrict__ sums2, int nRows) {
  int c = threadIdx.x;
  int rpb = (nRows + gridDim.x - 1) / gridDim.x;
  int r0 = blockIdx.x * rpb;
  int r1 = min(nRows, r0 + rpb);
  float s = 0.f, s2 = 0.f;
  for (int r = r0; r < r1; ++r) {
    float v = x[(size_t)r * 256 + c];
    s += v;
    s2 += v * v;
  }
  atomicAdd(&sums[c], s);
  atomicAdd(&sums2[c], s2);
}

__global__ void k_bnapply(float* __restrict__ x, ushort_t* __restrict__ x16,
                          const float* __restrict__ sums, const float* __restrict__ sums2,
                          const float* __restrict__ gamma, const float* __restrict__ betap,
                          int nRows) {
  int idx = blockIdx.x * 256 + threadIdx.x;
  if (idx >= nRows * 256) return;
  int c = idx & 255;
  float invN = 1.0f / (float)nRows;
  float mu = sums[c] * invN;
  float var = sums2[c] * invN - mu * mu;
  float v = (x[idx] - mu) * rsqrtf(var + EPS) * gamma[c] + betap[c];
  v = v >= 0.f ? v : 0.1f * v;   // LeakyReLU(0.1)
  x[idx] = v;
  x16[idx] = f2bf(v);
}

// ---------------- pooling + head -------------------------------------------
__global__ void k_pool(const float* __restrict__ x, const int* __restrict__ batch,
                       float* __restrict__ pool, int nRows) {
  int c = threadIdx.x;
  int rpb = (nRows + gridDim.x - 1) / gridDim.x;
  int r0 = blockIdx.x * rpb;
  int r1 = min(nRows, r0 + rpb);
  float acc = 0.f;
  int gc = -1;
  for (int r = r0; r < r1; ++r) {
    int g = batch[r];
    if (g != gc) {
      if (gc >= 0) atomicAdd(&pool[gc * 256 + c], acc);
      acc = 0.f;
      gc = g;
    }
    acc += x[(size_t)r * 256 + c];
  }
  if (gc >= 0) atomicAdd(&pool[gc * 256 + c], acc);
}

// batch is sorted -> per-graph counts via binary search (no atomics)
__global__ void k_counts_bs(const int* __restrict__ batch, float* __restrict__ counts,
                            int n, int G) {
  int g = threadIdx.x;
  if (g >= G) return;
  int lo = 0, hi = n;
  while (lo < hi) { int mid = (lo + hi) >> 1; if (batch[mid] < g) lo = mid + 1; else hi = mid; }
  int lb = lo;
  lo = 0; hi = n;
  while (lo < hi) { int mid = (lo + hi) >> 1; if (batch[mid] < g + 1) lo = mid + 1; else hi = mid; }
  counts[g] = (float)(lo - lb);
}

__global__ void k_head(const float* __restrict__ pool, const float* __restrict__ counts,
                       const float* __restrict__ hW, const float* __restrict__ hb,
                       float* __restrict__ outp) {
  int g = blockIdx.x, lane = threadIdx.x;
  float cnt = fmaxf(counts[g], 1.0f);
  float z = 0.f;
#pragma unroll
  for (int i = 0; i < 4; ++i) {
    int c = lane + i * 64;
    float s = pool[g * 256 + c];
    z += (s / cnt) * hW[c] + s * hW[256 + c];
  }
#pragma unroll
  for (int off = 1; off < 64; off <<= 1) z += __shfl_xor(z, off, 64);
  if (lane == 0) outp[g] = z + hb[0];
}

// ---------------------------------------------------------------------------
extern "C" void kernel_launch(void* const* d_in, const int* in_sizes, int n_in,
                              void* d_out, int out_size, void* d_ws, size_t ws_size,
                              hipStream_t stream) {
  const float* node_features = (const float*)d_in[0];
  const int*   edge_index    = (const int*)d_in[1];
  const float* edge_attr     = (const float*)d_in[2];
  const int*   batch         = (const int*)d_in[3];
  const float* proj_W  = (const float*)d_in[4];
  const float* proj_b  = (const float*)d_in[5];
  const float* Wq      = (const float*)d_in[6];
  const float* bq      = (const float*)d_in[7];
  const float* Wk      = (const float*)d_in[8];
  const float* bk      = (const float*)d_in[9];
  const float* Wv      = (const float*)d_in[10];
  const float* bv      = (const float*)d_in[11];
  const float* We      = (const float*)d_in[12];
  const float* be      = (const float*)d_in[13];
  const float* Wskip   = (const float*)d_in[14];
  const float* bskip   = (const float*)d_in[15];
  const float* Wbeta   = (const float*)d_in[16];
  const float* bn_gamma= (const float*)d_in[17];
  const float* bn_beta = (const float*)d_in[18];
  const float* head_W  = (const float*)d_in[19];
  const float* head_b  = (const float*)d_in[20];
  float* out_dev = (float*)d_out;

  const int Nn = in_sizes[0] / 64;   // 50000
  const int Ee = in_sizes[1] / 2;    // 500000
  const int Gg = out_size;           // 64

  char* ws = (char*)d_ws;
  size_t off = 0;
  auto alloc = [&](size_t bytes) -> void* {
    void* p = ws + off;
    off += (bytes + 255) & ~(size_t)255;
    return p;
  };
  float*    xb     = (float*)alloc((size_t)Nn * 256 * 4);
  float*    Qb     = (float*)alloc((size_t)Nn * 256 * 4);
  float*    Sb     = (float*)alloc((size_t)Nn * 256 * 4);
  ushort_t* KVb    = (ushort_t*)alloc((size_t)Nn * 512 * 2);   // interleaved K|V
  ushort_t* xb16   = (ushort_t*)alloc((size_t)Nn * 256 * 2);
  ushort_t* Wcat_t = (ushort_t*)alloc((size_t)4 * 1024 * 256 * 2);
  float*    bias_cat = (float*)alloc((size_t)4 * 1024 * 4);
  float*    bnstat = (float*)alloc(512 * 4);
  float*    pool   = (float*)alloc((size_t)Gg * 256 * 4);
  float*    counts = (float*)alloc((size_t)Gg * 4);
  int* deg     = (int*)alloc((size_t)Nn * 4);
  int* fill    = (int*)alloc((size_t)Nn * 4);
  int* row_ptr = (int*)alloc((size_t)(Nn + 1) * 4);
  int* csr     = (int*)alloc((size_t)Ee * 4);
  (void)ws_size; (void)n_in;

  const int* srcA = edge_index;
  const int* dstA = edge_index + Ee;

  // CSR build by dst
  hipMemsetAsync(deg, 0, (size_t)Nn * 4, stream);
  hipMemsetAsync(fill, 0, (size_t)Nn * 4, stream);
  k_count<<<(Ee + 255) / 256, 256, 0, stream>>>(dstA, deg, Ee);
  k_scan<<<1, 1024, 0, stream>>>(deg, row_ptr, Nn);
  k_scatter<<<(Ee + 255) / 256, 256, 0, stream>>>(dstA, row_ptr, fill, csr, Ee);

  // weight/bias conversion (bf16, transposed concat)
  k_wconv<<<dim3(8, 8, 16), dim3(32, 8), 0, stream>>>(Wq, Wk, Wv, Wskip, Wcat_t);
  k_bconv<<<16, 256, 0, stream>>>(bq, bk, bv, bskip, bias_cat);

  // input projection (fp32) + bf16 mirror
  dim3 gemm_grid(256 / BN, (Nn + BM - 1) / BM);
  k_gemm<<<gemm_grid, 256, 0, stream>>>(node_features, proj_W, proj_b, xb, xb16, Nn, 64, 256);

  int nodeBlocks = (Nn + 3) / 4;
  dim3 qkvs_grid(8, (Nn + 127) / 128);
  for (int l = 0; l < 4; ++l) {
    k_qkvs<<<qkvs_grid, 256, 0, stream>>>(xb16, Wcat_t + (size_t)l * 262144,
                                          bias_cat + l * 1024, Qb, KVb, Sb, Nn);

    k_attn<<<nodeBlocks, 256, 0, stream>>>(Qb, KVb, edge_attr, srcA,
                                           We + (size_t)l * 4096, be + l * 256,
                                           Wbeta + (size_t)l * 768,
                                           row_ptr, csr, Sb, xb, Nn);

    hipMemsetAsync(bnstat, 0, 512 * 4, stream);
    k_bnstats<<<256, 256, 0, stream>>>(xb, bnstat, bnstat + 256, Nn);
    k_bnapply<<<Nn, 256, 0, stream>>>(xb, xb16, bnstat, bnstat + 256,
                                      bn_gamma + l * 256, bn_beta + l * 256, Nn);
  }

  hipMemsetAsync(pool, 0, (size_t)Gg * 256 * 4, stream);
  hipMemsetAsync(counts, 0, (size_t)Gg * 4, stream);
  k_pool<<<256, 256, 0, stream>>>(xb, batch, pool, Nn);
  k_counts_bs<<<1, 64, 0, stream>>>(batch, counts, Nn, Gg);
  k_head<<<Gg, 64, 0, stream>>>(pool, counts, head_W, head_b, out_dev);
}

// Round 5
// 1601.720 us; speedup vs baseline: 2.7237x; 1.0596x over previous
//
#include <hip/hip_runtime.h>
#include <math.h>

// ---------------------------------------------------------------------------
// AnticipatoryRestaurantGNN round 5:
//  - dq/qbe folded into the fused QKVS GEMM via composite weights
//    (M = Wq @ We'^T / 8), GEMM cols 1024 -> 1152
//  - k_attn: dual even/odd online-softmax chains (2x ILP on serial chain)
//  - k_bnapply grid-stride (was 50000 tiny blocks -> dispatch-bound)
// ---------------------------------------------------------------------------

#define EPS 1e-5f
typedef unsigned short ushort_t;
typedef unsigned int uint_t;

using f32x4 = __attribute__((ext_vector_type(4))) float;
using s16x8 = __attribute__((ext_vector_type(8))) short;
using u16x8 = __attribute__((ext_vector_type(8))) unsigned short;

__device__ __forceinline__ ushort_t f2bf(float f) {
  union { float f; uint_t u; } v; v.f = f;
  uint_t u = v.u;
  uint_t r = (u + 0x7FFFu + ((u >> 16) & 1u)) >> 16;   // RNE
  return (ushort_t)r;
}
__device__ __forceinline__ float bf2f(ushort_t h) {
  union { uint_t u; float f; } v; v.u = ((uint_t)h) << 16;
  return v.f;
}

__device__ __forceinline__ void gl_lds16(const void* g, void* l) {
  __builtin_amdgcn_global_load_lds(
      (const __attribute__((address_space(1))) void*)g,
      (__attribute__((address_space(3))) void*)l, 16, 0, 0);
}

__device__ __forceinline__ float red16(float x) {
  x += __shfl_xor(x, 1, 64);
  x += __shfl_xor(x, 2, 64);
  x += __shfl_xor(x, 4, 64);
  x += __shfl_xor(x, 8, 64);
  return x;
}

// ---------------- CSR build (by dst; dst reused across all 4 layers) -------
__global__ void k_count(const int* __restrict__ dst, int* __restrict__ deg, int n) {
  int i = blockIdx.x * 256 + threadIdx.x;
  if (i < n) atomicAdd(&deg[dst[i]], 1);
}

__global__ void k_scan(const int* __restrict__ deg, int* __restrict__ row_ptr, int n) {
  __shared__ int wsum[16];
  __shared__ int carry_s;
  int t = threadIdx.x, lane = t & 63, w = t >> 6;
  if (t == 0) { carry_s = 0; row_ptr[0] = 0; }
  __syncthreads();
  for (int base = 0; base < n; base += 1024) {
    int v = (base + t < n) ? deg[base + t] : 0;
    int x = v;
#pragma unroll
    for (int off = 1; off < 64; off <<= 1) {
      int y = __shfl_up(x, off, 64);
      if (lane >= off) x += y;
    }
    if (lane == 63) wsum[w] = x;
    __syncthreads();
    if (w == 0 && lane < 16) {
      int s = wsum[lane];
#pragma unroll
      for (int off = 1; off < 16; off <<= 1) {
        int y = __shfl_up(s, off, 64);
        if (lane >= off) s += y;
      }
      wsum[lane] = s;
    }
    __syncthreads();
    int add = (w > 0) ? wsum[w - 1] : 0;
    int incl = x + add + carry_s;
    if (base + t < n) row_ptr[base + t + 1] = incl;
    __syncthreads();
    if (t == 1023) carry_s = incl;
    __syncthreads();
  }
}

__global__ void k_scatter(const int* __restrict__ dst, const int* __restrict__ row_ptr,
                          int* __restrict__ fill, int* __restrict__ csr, int n) {
  int i = blockIdx.x * 256 + threadIdx.x;
  if (i < n) {
    int d = dst[i];
    int pos = atomicAdd(&fill[d], 1);
    csr[row_ptr[d] + pos] = i;
  }
}

// ---------------- weight convert: Wcat_t[l][n=1152][k=256] bf16 ------------
__global__ void k_wconv(const float* __restrict__ Wq, const float* __restrict__ Wk,
                        const float* __restrict__ Wv, const float* __restrict__ Ws,
                        ushort_t* __restrict__ Wcat_t) {
  __shared__ float tile[32][33];
  int l = blockIdx.z >> 2, sel = blockIdx.z & 3;
  const float* W = (sel == 0) ? Wq : (sel == 1) ? Wk : (sel == 2) ? Wv : Ws;
  W += (size_t)l * 65536;
  int k0 = blockIdx.x * 32, n0 = blockIdx.y * 32;
  int tx = threadIdx.x, ty = threadIdx.y;           // 32 x 8
#pragma unroll
  for (int i = 0; i < 32; i += 8) tile[ty + i][tx] = W[(size_t)(k0 + ty + i) * 256 + n0 + tx];
  __syncthreads();
  ushort_t* dst = Wcat_t + (size_t)l * (1152 * 256) + (size_t)(sel * 256 + n0) * 256 + k0;
#pragma unroll
  for (int i = 0; i < 32; i += 8) dst[(size_t)(ty + i) * 256 + tx] = f2bf(tile[tx][ty + i]);
}

// composite rows 1024..1091: M[ci][j] = sum_{c in head(j)} Wq[ci][c]*w2[c]
//   j<64: h=j>>4, t=j&15, w2 = We[t][64h..]/8;  j=64+h: w2 = be[64h..]/8
// bias d0[j] = sum bq[c]*w2[c]  -> bias_cat[l*1152 + 1024 + j]
__global__ void k_mkdq(const float* __restrict__ Wq, const float* __restrict__ bq,
                       const float* __restrict__ We, const float* __restrict__ be,
                       ushort_t* __restrict__ Wcat_t, float* __restrict__ bias_cat) {
  int j = blockIdx.x;        // 0..67
  int l = blockIdx.y;        // 0..3
  int ci = threadIdx.x;      // 0..255
  __shared__ float w2[64];
  int h = (j < 64) ? (j >> 4) : (j - 64);
  if (ci < 64) {
    float v;
    if (j < 64) v = We[(size_t)l * 4096 + (j & 15) * 256 + h * 64 + ci];
    else        v = be[l * 256 + h * 64 + ci];
    w2[ci] = v * 0.125f;
  }
  __syncthreads();
  const float* Wq_l = Wq + (size_t)l * 65536;
  float acc = 0.f;
#pragma unroll 8
  for (int c = 0; c < 64; ++c) acc += Wq_l[(size_t)ci * 256 + h * 64 + c] * w2[c];
  Wcat_t[(size_t)l * (1152 * 256) + (size_t)(1024 + j) * 256 + ci] = f2bf(acc);
  if (ci == 0) {
    const float* bq_l = bq + l * 256;
    float d0 = 0.f;
    for (int c = 0; c < 64; ++c) d0 += bq_l[h * 64 + c] * w2[c];
    bias_cat[l * 1152 + 1024 + j] = d0;
  }
}

__global__ void k_bconv(const float* __restrict__ bq, const float* __restrict__ bk,
                        const float* __restrict__ bv, const float* __restrict__ bs,
                        float* __restrict__ bias_cat) {
  int idx = blockIdx.x * 256 + threadIdx.x;   // 4096 total
  if (idx >= 4096) return;
  int l = idx >> 10, rest = idx & 1023, sel = rest >> 8, c = rest & 255;
  const float* p = (sel == 0) ? bq : (sel == 1) ? bk : (sel == 2) ? bv : bs;
  bias_cat[l * 1152 + rest] = p[l * 256 + c];
}

// ---------------- fp32 tiled GEMM (input projection only) ------------------
#define BM 128
#define BN 64
#define BK 16
__global__ __launch_bounds__(256) void k_gemm(
    const float* __restrict__ A, const float* __restrict__ B,
    const float* __restrict__ bias, float* __restrict__ C,
    ushort_t* __restrict__ C16, int M, int Kd, int Nd) {
  __shared__ float As[BK][BM + 4];
  __shared__ float Bs[BK][BN + 4];
  int t = threadIdx.x;
  int tx = t & 15, ty = t >> 4;
  int row0 = blockIdx.y * BM, col0 = blockIdx.x * BN;
  float acc[8][4] = {};
  for (int k0 = 0; k0 < Kd; k0 += BK) {
#pragma unroll
    for (int i = 0; i < 2; ++i) {
      int idx = t + i * 256;
      int r = idx >> 2, kk = (idx & 3) * 4;
      float4 a = make_float4(0.f, 0.f, 0.f, 0.f);
      if (row0 + r < M) a = *(const float4*)(A + (size_t)(row0 + r) * Kd + k0 + kk);
      As[kk + 0][r] = a.x; As[kk + 1][r] = a.y; As[kk + 2][r] = a.z; As[kk + 3][r] = a.w;
    }
    {
      int kk = t >> 4, cc = (t & 15) * 4;
      float4 b = *(const float4*)(B + (size_t)(k0 + kk) * Nd + col0 + cc);
      Bs[kk][cc] = b.x; Bs[kk][cc + 1] = b.y; Bs[kk][cc + 2] = b.z; Bs[kk][cc + 3] = b.w;
    }
    __syncthreads();
#pragma unroll
    for (int kk = 0; kk < BK; ++kk) {
      float ar[8], br[4];
#pragma unroll
      for (int i = 0; i < 8; ++i) ar[i] = As[kk][ty * 8 + i];
#pragma unroll
      for (int j = 0; j < 4; ++j) br[j] = Bs[kk][tx * 4 + j];
#pragma unroll
      for (int i = 0; i < 8; ++i)
#pragma unroll
        for (int j = 0; j < 4; ++j) acc[i][j] += ar[i] * br[j];
    }
    __syncthreads();
  }
#pragma unroll
  for (int i = 0; i < 8; ++i) {
    int r = row0 + ty * 8 + i;
    if (r < M) {
      int c = col0 + tx * 4;
      float4 o;
      o.x = acc[i][0] + bias[c + 0];
      o.y = acc[i][1] + bias[c + 1];
      o.z = acc[i][2] + bias[c + 2];
      o.w = acc[i][3] + bias[c + 3];
      *(float4*)(C + (size_t)r * Nd + c) = o;
      ushort4 h;
      h.x = f2bf(o.x); h.y = f2bf(o.y); h.z = f2bf(o.z); h.w = f2bf(o.w);
      *(ushort4*)(C16 + (size_t)r * Nd + c) = h;
    }
  }
}

// ---------------- fused QKVS+Dq bf16 MFMA GEMM -----------------------------
// C[M x 1152] = A[M x 256] @ Bt^T  (Bt is [1152][256], k-contiguous)
__global__ __launch_bounds__(256) void k_qkvs(
    const ushort_t* __restrict__ A, const ushort_t* __restrict__ Bt,
    const float* __restrict__ bias, float* __restrict__ Qb,
    ushort_t* __restrict__ KVb, float* __restrict__ Sb,
    float* __restrict__ Dqb, int M) {
  __shared__ short lds_a[8192];   // 128 x 64 bf16 (swizzled granules)
  __shared__ short lds_b[8192];
  int t = threadIdx.x;
  int lane = t & 63, wv = t >> 6;
  int row0 = blockIdx.y * 128, col0 = blockIdx.x * 128;

  f32x4 acc[4][4];
#pragma unroll
  for (int im = 0; im < 4; ++im)
#pragma unroll
    for (int in = 0; in < 4; ++in) acc[im][in] = (f32x4){0.f, 0.f, 0.f, 0.f};

  int ln16 = lane & 15, q = lane >> 4;
  int mbase = (wv >> 1) * 64;
  int nbase = (wv & 1) * 64;

  for (int kk = 0; kk < 4; ++kk) {
    int k0 = kk * 64;
    __syncthreads();          // protect previous iteration's LDS reads
#pragma unroll
    for (int i = 0; i < 4; ++i) {
      int gi = i * 256 + t;
      int r = gi >> 3, c = (gi & 7) ^ (r & 7);
      int gr = row0 + r; if (gr > M - 1) gr = M - 1;
      gl_lds16(A + (size_t)gr * 256 + k0 + c * 8, &((int4*)lds_a)[gi]);
      gl_lds16(Bt + (size_t)(col0 + r) * 256 + k0 + c * 8, &((int4*)lds_b)[gi]);
    }
    __syncthreads();          // drains vmcnt(0) then barrier
#pragma unroll
    for (int kc = 0; kc < 2; ++kc) {
      s16x8 af[4], bf[4];
      int cq = kc * 4 + q;
#pragma unroll
      for (int im = 0; im < 4; ++im) {
        int r = mbase + im * 16 + ln16;
        af[im] = ((const s16x8*)lds_a)[r * 8 + (cq ^ (r & 7))];
      }
#pragma unroll
      for (int in = 0; in < 4; ++in) {
        int r = nbase + in * 16 + ln16;
        bf[in] = ((const s16x8*)lds_b)[r * 8 + (cq ^ (r & 7))];
      }
#pragma unroll
      for (int im = 0; im < 4; ++im)
#pragma unroll
        for (int in = 0; in < 4; ++in)
          acc[im][in] = __builtin_amdgcn_mfma_f32_16x16x32_bf16(af[im], bf[in], acc[im][in], 0, 0, 0);
    }
  }

  // epilogue: C[m = q*4+j][n = ln16] per tile.
#pragma unroll
  for (int in = 0; in < 4; ++in) {
    int ncol = col0 + nbase + in * 16 + ln16;
    int lc = ncol & 255;
    float bz = bias[ncol];
#pragma unroll
    for (int im = 0; im < 4; ++im) {
#pragma unroll
      for (int j = 0; j < 4; ++j) {
        int mr = row0 + mbase + im * 16 + q * 4 + j;
        if (mr < M) {
          float v = acc[im][in][j] + bz;
          if (ncol < 256)       Qb[(size_t)mr * 256 + lc] = v;
          else if (ncol < 512)  KVb[(size_t)mr * 512 + (lc >> 2) * 8 + (lc & 3)] = f2bf(v);
          else if (ncol < 768)  KVb[(size_t)mr * 512 + (lc >> 2) * 8 + (lc & 3) + 4] = f2bf(v);
          else if (ncol < 1024) Sb[(size_t)mr * 256 + lc] = v;
          else { int j2 = ncol - 1024; if (j2 < 68) Dqb[(size_t)mr * 68 + j2] = v; }
        }
      }
    }
  }
}

// ---------------- attention + beta-gate blend: one wave per dst node -------
// score_h = qs.K[s] + ea_j[t]*dq[t,h] (via red16) + qbe_h ; dq/qbe from Dqb.
// Dual even/odd online-softmax chains, merged at the end (flash-merge).
__global__ __launch_bounds__(256) void k_attn(
    const float* __restrict__ Qp, const ushort_t* __restrict__ KVm,
    const float* __restrict__ Dqp,
    const float* __restrict__ ea_g, const int* __restrict__ srcA,
    const float* __restrict__ We_l, const float* __restrict__ be_l,
    const float* __restrict__ Wb, const int* __restrict__ row_ptr,
    const int* __restrict__ csr, const float* __restrict__ Sp,
    float* __restrict__ xout, int nNodes) {
  __shared__ float sWb[768];
  __shared__ float ea_s[4 * 1088];   // per-wave 64 edges x 17 (padded)
  int t = threadIdx.x;
  sWb[t] = Wb[t];
  sWb[t + 256] = Wb[t + 256];
  sWb[t + 512] = Wb[t + 512];
  __syncthreads();
  int lane = t & 63;
  int t16 = lane & 15;
  int n = blockIdx.x * 4 + (t >> 6);
  if (n >= nNodes) return;
  float* eaw = ea_s + (t >> 6) * 1088;

  float4 be4 = *(const float4*)(be_l + 4 * lane);
  float4 qs = *(const float4*)(Qp + (size_t)n * 256 + 4 * lane);
  qs.x *= 0.125f; qs.y *= 0.125f; qs.z *= 0.125f; qs.w *= 0.125f;

  float dqv = Dqp[(size_t)n * 68 + lane];
  float qbe = Dqp[(size_t)n * 68 + 64 + (lane >> 4)];

  int beg = row_ptr[n], end = row_ptr[n + 1];
  float m2[2] = {-INFINITY, -INFINITY};
  float dn[2] = {0.f, 0.f};
  float wa[2] = {0.f, 0.f};
  float4 ac[2] = {make_float4(0.f, 0.f, 0.f, 0.f), make_float4(0.f, 0.f, 0.f, 0.f)};

  for (int base = beg; base < end; base += 64) {
    int cnt = min(64, end - base);
    int eL = 0, sL = 0;
    if (lane < cnt) { eL = csr[base + lane]; sL = srcA[eL]; }
    if (lane < cnt) {
      const float4* eap = (const float4*)(ea_g + (size_t)eL * 16);
      float4 e0 = eap[0], e1 = eap[1], e2 = eap[2], e3 = eap[3];
      float* dst = eaw + lane * 17;
      dst[0] = e0.x; dst[1] = e0.y; dst[2] = e0.z; dst[3] = e0.w;
      dst[4] = e1.x; dst[5] = e1.y; dst[6] = e1.z; dst[7] = e1.w;
      dst[8] = e2.x; dst[9] = e2.y; dst[10] = e2.z; dst[11] = e2.w;
      dst[12] = e3.x; dst[13] = e3.y; dst[14] = e3.z; dst[15] = e3.w;
    }

    u16x8 bufA[4], bufB[4];
    auto ld4 = [&](u16x8* buf, int j0) {
#pragma unroll
      for (int jj = 0; jj < 4; ++jj) {
        int idx = j0 + jj;
        int s = __shfl(sL, idx & 63, 64);
        if (idx < cnt) buf[jj] = *(const u16x8*)(KVm + (size_t)s * 512 + lane * 8);
      }
    };
    auto proc = [&](const u16x8& kv, int idx, int ch) {
      float eat = eaw[idx * 17 + t16];
      float part = qs.x * bf2f(kv[0]) + qs.y * bf2f(kv[1]) +
                   qs.z * bf2f(kv[2]) + qs.w * bf2f(kv[3]) + eat * dqv;
      float p = red16(part) + qbe;
      float mn = fmaxf(m2[ch], p);
      float scl = __expf(m2[ch] - mn);   // -inf first time -> 0
      float w = __expf(p - mn);
      m2[ch] = mn;
      dn[ch] = dn[ch] * scl + w;
      ac[ch].x = ac[ch].x * scl + w * bf2f(kv[4]);
      ac[ch].y = ac[ch].y * scl + w * bf2f(kv[5]);
      ac[ch].z = ac[ch].z * scl + w * bf2f(kv[6]);
      ac[ch].w = ac[ch].w * scl + w * bf2f(kv[7]);
      wa[ch] = wa[ch] * scl + w * eat;
    };

    ld4(bufA, 0);
    for (int j0 = 0; j0 < cnt; j0 += 8) {
      ld4(bufB, j0 + 4);
#pragma unroll
      for (int jj = 0; jj < 4; ++jj) if (j0 + jj < cnt) proc(bufA[jj], j0 + jj, jj & 1);
      if (j0 + 4 >= cnt) break;
      ld4(bufA, j0 + 8);
#pragma unroll
      for (int jj = 0; jj < 4; ++jj) if (j0 + 4 + jj < cnt) proc(bufB[jj], j0 + 4 + jj, jj & 1);
    }
  }

  float4 o = make_float4(0.f, 0.f, 0.f, 0.f);
  if (end > beg) {
    // merge chains (chain0 non-empty whenever end>beg)
    float M = fmaxf(m2[0], m2[1]);
    float s0 = __expf(m2[0] - M), s1 = __expf(m2[1] - M);
    float denom = dn[0] * s0 + dn[1] * s1;
    float inv = 1.0f / denom;
    float wacc = (wa[0] * s0 + wa[1] * s1) * inv;
    o.x = (ac[0].x * s0 + ac[1].x * s1) * inv + be4.x;
    o.y = (ac[0].y * s0 + ac[1].y * s1) * inv + be4.y;
    o.z = (ac[0].z * s0 + ac[1].z * s1) * inv + be4.z;
    o.w = (ac[0].w * s0 + ac[1].w * s1) * inv + be4.w;
    int lanebase = lane & 48;
#pragma unroll
    for (int tt = 0; tt < 16; ++tt) {
      float wv = __shfl(wacc, lanebase + tt, 64);
      float4 w4 = *(const float4*)(We_l + tt * 256 + 4 * lane);
      o.x += wv * w4.x; o.y += wv * w4.y; o.z += wv * w4.z; o.w += wv * w4.w;
    }
  }

  // fused beta-gate blend
  float4 r = *(const float4*)(Sp + (size_t)n * 256 + 4 * lane);
  int c = 4 * lane;
  float z = o.x * sWb[c] + o.y * sWb[c + 1] + o.z * sWb[c + 2] + o.w * sWb[c + 3]
          + r.x * sWb[256 + c] + r.y * sWb[257 + c] + r.z * sWb[258 + c] + r.w * sWb[259 + c]
          + (o.x - r.x) * sWb[512 + c] + (o.y - r.y) * sWb[513 + c]
          + (o.z - r.z) * sWb[514 + c] + (o.w - r.w) * sWb[515 + c];
#pragma unroll
  for (int off = 1; off < 64; off <<= 1) z += __shfl_xor(z, off, 64);
  float beta = 1.0f / (1.0f + __expf(-z));
  float4 xn;
  xn.x = beta * r.x + (1.f - beta) * o.x;
  xn.y = beta * r.y + (1.f - beta) * o.y;
  xn.z = beta * r.z + (1.f - beta) * o.z;
  xn.w = beta * r.w + (1.f - beta) * o.w;
  *(float4*)(xout + (size_t)n * 256 + 4 * lane) = xn;
}

// ---------------- batchnorm ------------------------------------------------
__global__ void k_bnstats(const float* __restrict__ x, float* __restrict__ sums,
                          float* __restrict__ sums2, int nRows) {
  int c = threadIdx.x;
  int rpb = (nRows + gridDim.x - 1) / gridDim.x;
  int r0 = blockIdx.x * rpb;
  int r1 = min(nRows, r0 + rpb);
  float s = 0.f, s2 = 0.f;
  for (int r = r0; r < r1; ++r) {
    float v = x[(size_t)r * 256 + c];
    s += v;
    s2 += v * v;
  }
  atomicAdd(&sums[c], s);
  atomicAdd(&sums2[c], s2);
}

__global__ __launch_bounds__(256) void k_bnapply(
    float* __restrict__ x, ushort_t* __restrict__ x16,
    const float* __restrict__ sums, const float* __restrict__ sums2,
    const float* __restrict__ gamma, const float* __restrict__ betap, int nRows) {
  int total4 = nRows * 64;
  float invN = 1.0f / (float)nRows;
  for (int i4 = blockIdx.x * 256 + threadIdx.x; i4 < total4; i4 += gridDim.x * 256) {
    int c4 = (i4 & 63) * 4;
    float4 xv = *(const float4*)(x + (size_t)i4 * 4);
    float4 s = *(const float4*)(sums + c4);
    float4 s2 = *(const float4*)(sums2 + c4);
    float4 g = *(const float4*)(gamma + c4);
    float4 b = *(const float4*)(betap + c4);
    float mu0 = s.x * invN, mu1 = s.y * invN, mu2 = s.z * invN, mu3 = s.w * invN;
    float sc0 = rsqrtf(s2.x * invN - mu0 * mu0 + EPS) * g.x;
    float sc1 = rsqrtf(s2.y * invN - mu1 * mu1 + EPS) * g.y;
    float sc2 = rsqrtf(s2.z * invN - mu2 * mu2 + EPS) * g.z;
    float sc3 = rsqrtf(s2.w * invN - mu3 * mu3 + EPS) * g.w;
    float4 v;
    v.x = (xv.x - mu0) * sc0 + b.x;
    v.y = (xv.y - mu1) * sc1 + b.y;
    v.z = (xv.z - mu2) * sc2 + b.z;
    v.w = (xv.w - mu3) * sc3 + b.w;
    v.x = v.x >= 0.f ? v.x : 0.1f * v.x;
    v.y = v.y >= 0.f ? v.y : 0.1f * v.y;
    v.z = v.z >= 0.f ? v.z : 0.1f * v.z;
    v.w = v.w >= 0.f ? v.w : 0.1f * v.w;
    *(float4*)(x + (size_t)i4 * 4) = v;
    ushort4 h;
    h.x = f2bf(v.x); h.y = f2bf(v.y); h.z = f2bf(v.z); h.w = f2bf(v.w);
    *(ushort4*)(x16 + (size_t)i4 * 4) = h;
  }
}

// ---------------- pooling + head -------------------------------------------
__global__ void k_pool(const float* __restrict__ x, const int* __restrict__ batch,
                       float* __restrict__ pool, int nRows) {
  int c = threadIdx.x;
  int rpb = (nRows + gridDim.x - 1) / gridDim.x;
  int r0 = blockIdx.x * rpb;
  int r1 = min(nRows, r0 + rpb);
  float acc = 0.f;
  int gc = -1;
  for (int r = r0; r < r1; ++r) {
    int g = batch[r];
    if (g != gc) {
      if (gc >= 0) atomicAdd(&pool[gc * 256 + c], acc);
      acc = 0.f;
      gc = g;
    }
    acc += x[(size_t)r * 256 + c];
  }
  if (gc >= 0) atomicAdd(&pool[gc * 256 + c], acc);
}

// batch is sorted -> per-graph counts via binary search (no atomics)
__global__ void k_counts_bs(const int* __restrict__ batch, float* __restrict__ counts,
                            int n, int G) {
  int g = threadIdx.x;
  if (g >= G) return;
  int lo = 0, hi = n;
  while (lo < hi) { int mid = (lo + hi) >> 1; if (batch[mid] < g) lo = mid + 1; else hi = mid; }
  int lb = lo;
  lo = 0; hi = n;
  while (lo < hi) { int mid = (lo + hi) >> 1; if (batch[mid] < g + 1) lo = mid + 1; else hi = mid; }
  counts[g] = (float)(lo - lb);
}

__global__ void k_head(const float* __restrict__ pool, const float* __restrict__ counts,
                       const float* __restrict__ hW, const float* __restrict__ hb,
                       float* __restrict__ outp) {
  int g = blockIdx.x, lane = threadIdx.x;
  float cnt = fmaxf(counts[g], 1.0f);
  float z = 0.f;
#pragma unroll
  for (int i = 0; i < 4; ++i) {
    int c = lane + i * 64;
    float s = pool[g * 256 + c];
    z += (s / cnt) * hW[c] + s * hW[256 + c];
  }
#pragma unroll
  for (int off = 1; off < 64; off <<= 1) z += __shfl_xor(z, off, 64);
  if (lane == 0) outp[g] = z + hb[0];
}

// ---------------------------------------------------------------------------
extern "C" void kernel_launch(void* const* d_in, const int* in_sizes, int n_in,
                              void* d_out, int out_size, void* d_ws, size_t ws_size,
                              hipStream_t stream) {
  const float* node_features = (const float*)d_in[0];
  const int*   edge_index    = (const int*)d_in[1];
  const float* edge_attr     = (const float*)d_in[2];
  const int*   batch         = (const int*)d_in[3];
  const float* proj_W  = (const float*)d_in[4];
  const float* proj_b  = (const float*)d_in[5];
  const float* Wq      = (const float*)d_in[6];
  const float* bq      = (const float*)d_in[7];
  const float* Wk      = (const float*)d_in[8];
  const float* bk      = (const float*)d_in[9];
  const float* Wv      = (const float*)d_in[10];
  const float* bv      = (const float*)d_in[11];
  const float* We      = (const float*)d_in[12];
  const float* be      = (const float*)d_in[13];
  const float* Wskip   = (const float*)d_in[14];
  const float* bskip   = (const float*)d_in[15];
  const float* Wbeta   = (const float*)d_in[16];
  const float* bn_gamma= (const float*)d_in[17];
  const float* bn_beta = (const float*)d_in[18];
  const float* head_W  = (const float*)d_in[19];
  const float* head_b  = (const float*)d_in[20];
  float* out_dev = (float*)d_out;

  const int Nn = in_sizes[0] / 64;   // 50000
  const int Ee = in_sizes[1] / 2;    // 500000
  const int Gg = out_size;           // 64

  char* ws = (char*)d_ws;
  size_t off = 0;
  auto alloc = [&](size_t bytes) -> void* {
    void* p = ws + off;
    off += (bytes + 255) & ~(size_t)255;
    return p;
  };
  float*    xb     = (float*)alloc((size_t)Nn * 256 * 4);
  float*    Qb     = (float*)alloc((size_t)Nn * 256 * 4);
  float*    Sb     = (float*)alloc((size_t)Nn * 256 * 4);
  float*    Dqb    = (float*)alloc((size_t)Nn * 68 * 4);
  ushort_t* KVb    = (ushort_t*)alloc((size_t)Nn * 512 * 2);   // interleaved K|V
  ushort_t* xb16   = (ushort_t*)alloc((size_t)Nn * 256 * 2);
  ushort_t* Wcat_t = (ushort_t*)alloc((size_t)4 * 1152 * 256 * 2);
  float*    bias_cat = (float*)alloc((size_t)4 * 1152 * 4);
  float*    bnstat = (float*)alloc(512 * 4);
  float*    pool   = (float*)alloc((size_t)Gg * 256 * 4);
  float*    counts = (float*)alloc((size_t)Gg * 4);
  int* deg     = (int*)alloc((size_t)Nn * 4);
  int* fill    = (int*)alloc((size_t)Nn * 4);
  int* row_ptr = (int*)alloc((size_t)(Nn + 1) * 4);
  int* csr     = (int*)alloc((size_t)Ee * 4);
  (void)ws_size; (void)n_in;

  const int* srcA = edge_index;
  const int* dstA = edge_index + Ee;

  // CSR build by dst
  hipMemsetAsync(deg, 0, (size_t)Nn * 4, stream);
  hipMemsetAsync(fill, 0, (size_t)Nn * 4, stream);
  k_count<<<(Ee + 255) / 256, 256, 0, stream>>>(dstA, deg, Ee);
  k_scan<<<1, 1024, 0, stream>>>(deg, row_ptr, Nn);
  k_scatter<<<(Ee + 255) / 256, 256, 0, stream>>>(dstA, row_ptr, fill, csr, Ee);

  // weight/bias conversion (bf16, transposed concat) + composite dq rows
  k_wconv<<<dim3(8, 8, 16), dim3(32, 8), 0, stream>>>(Wq, Wk, Wv, Wskip, Wcat_t);
  k_bconv<<<16, 256, 0, stream>>>(bq, bk, bv, bskip, bias_cat);
  k_mkdq<<<dim3(68, 4), 256, 0, stream>>>(Wq, bq, We, be, Wcat_t, bias_cat);

  // input projection (fp32) + bf16 mirror
  dim3 gemm_grid(256 / BN, (Nn + BM - 1) / BM);
  k_gemm<<<gemm_grid, 256, 0, stream>>>(node_features, proj_W, proj_b, xb, xb16, Nn, 64, 256);

  int nodeBlocks = (Nn + 3) / 4;
  dim3 qkvs_grid(9, (Nn + 127) / 128);
  for (int l = 0; l < 4; ++l) {
    k_qkvs<<<qkvs_grid, 256, 0, stream>>>(xb16, Wcat_t + (size_t)l * (1152 * 256),
                                          bias_cat + l * 1152, Qb, KVb, Sb, Dqb, Nn);

    k_attn<<<nodeBlocks, 256, 0, stream>>>(Qb, KVb, Dqb, edge_attr, srcA,
                                           We + (size_t)l * 4096, be + l * 256,
                                           Wbeta + (size_t)l * 768,
                                           row_ptr, csr, Sb, xb, Nn);

    hipMemsetAsync(bnstat, 0, 512 * 4, stream);
    k_bnstats<<<256, 256, 0, stream>>>(xb, bnstat, bnstat + 256, Nn);
    k_bnapply<<<512, 256, 0, stream>>>(xb, xb16, bnstat, bnstat + 256,
                                       bn_gamma + l * 256, bn_beta + l * 256, Nn);
  }

  hipMemsetAsync(pool, 0, (size_t)Gg * 256 * 4, stream);
  hipMemsetAsync(counts, 0, (size_t)Gg * 4, stream);
  k_pool<<<256, 256, 0, stream>>>(xb, batch, pool, Nn);
  k_counts_bs<<<1, 64, 0, stream>>>(batch, counts, Nn, Gg);
  k_head<<<Gg, 64, 0, stream>>>(pool, counts, head_W, head_b, out_dev);
}